// Round 1
// baseline (2023.357 us; speedup 1.0000x reference)
//
#include <hip/hip_runtime.h>
#include <hip/hip_bf16.h>

#define NNODES 20000
#define EEDGES 320000
#define FIN 1024
#define HMID 256
#define DOUT 128

typedef __bf16 bf16x8 __attribute__((ext_vector_type(8)));
typedef __bf16 bf16x4 __attribute__((ext_vector_type(4)));
typedef float f32x4 __attribute__((ext_vector_type(4)));

// ---------------- weight prep ----------------
// W_gcn [FIN][HMID] fp32 -> Wt [HMID][FIN] bf16 (transposed for B-fragment 16B loads)
__global__ void k_prep_wgcn(const float* __restrict__ W, __bf16* __restrict__ Wt) {
    int tid = blockIdx.x * 256 + threadIdx.x;
    if (tid >= FIN * HMID) return;
    int k = tid >> 8;      // row in W (0..1023)
    int n = tid & 255;     // col in W (0..255)
    Wt[(size_t)n * FIN + k] = (__bf16)W[tid];
}

// Wq/Wk/Wv/Ws [HMID][DOUT] fp32 -> Wallt [512][HMID] bf16 stacked transposed; biases -> ball[512]
__global__ void k_prep_watt(const float* __restrict__ Wq, const float* __restrict__ Wk,
                            const float* __restrict__ Wv, const float* __restrict__ Ws,
                            const float* __restrict__ bq, const float* __restrict__ bk,
                            const float* __restrict__ bv, const float* __restrict__ bs,
                            __bf16* __restrict__ Wallt, float* __restrict__ ball) {
    int g = blockIdx.y;
    const float* W = (g == 0) ? Wq : (g == 1) ? Wk : (g == 2) ? Wv : Ws;
    int tid = blockIdx.x * 256 + threadIdx.x;
    if (tid < HMID * DOUT) {
        int k = tid >> 7;   // 0..255
        int n = tid & 127;  // 0..127
        Wallt[(size_t)(g * DOUT + n) * HMID + k] = (__bf16)W[tid];
    }
    if (tid < DOUT) {
        const float* b = (g == 0) ? bq : (g == 1) ? bk : (g == 2) ? bv : bs;
        ball[g * DOUT + tid] = b[tid];
    }
}

// ---------------- degree / norm ----------------
__global__ void k_deg_init(float* __restrict__ deg, float* __restrict__ S) {
    int i = blockIdx.x * 256 + threadIdx.x;
    if (i < NNODES) deg[i] = 1.0f;   // self loop
    if (i < 8) S[i] = 0.0f;
}

__global__ void k_deg_acc(const int* __restrict__ dst, float* __restrict__ deg) {
    int e = blockIdx.x * 256 + threadIdx.x;
    if (e < EEDGES) atomicAdd(&deg[dst[e]], 1.0f);
}

__global__ void k_dinv(const float* __restrict__ deg, float* __restrict__ dinv) {
    int i = blockIdx.x * 256 + threadIdx.x;
    if (i < NNODES) dinv[i] = rsqrtf(deg[i]);
}

// ---------------- GEMM1: h0 = x @ W_gcn  (bf16 MFMA, fp32 out) ----------------
// block = 4 waves -> 64 rows x 128 cols; grid (ceil(N/64), HMID/128)
__global__ __launch_bounds__(256) void k_gemm1(const float* __restrict__ x,
                                               const __bf16* __restrict__ Wt,
                                               float* __restrict__ h0) {
    int lane = threadIdx.x & 63;
    int wave = threadIdx.x >> 6;
    int m = lane & 15;
    int q = lane >> 4;  // 0..3
    int r0 = blockIdx.x * 64 + wave * 16;
    int c0 = blockIdx.y * 128;
    int row = r0 + m; if (row > NNODES - 1) row = NNODES - 1;
    const float* xp = x + (size_t)row * FIN + q * 8;
    f32x4 acc[8] = {};
    for (int k0 = 0; k0 < FIN; k0 += 32) {
        const float4* ap = (const float4*)(xp + k0);
        float4 a0 = ap[0], a1 = ap[1];
        bf16x8 a;
        a[0] = (__bf16)a0.x; a[1] = (__bf16)a0.y; a[2] = (__bf16)a0.z; a[3] = (__bf16)a0.w;
        a[4] = (__bf16)a1.x; a[5] = (__bf16)a1.y; a[6] = (__bf16)a1.z; a[7] = (__bf16)a1.w;
#pragma unroll
        for (int t = 0; t < 8; t++) {
            bf16x8 b = *(const bf16x8*)(Wt + (size_t)(c0 + t * 16 + m) * FIN + k0 + q * 8);
            acc[t] = __builtin_amdgcn_mfma_f32_16x16x32_bf16(a, b, acc[t], 0, 0, 0);
        }
    }
#pragma unroll
    for (int t = 0; t < 8; t++) {
#pragma unroll
        for (int r = 0; r < 4; r++) {
            int rr = r0 + q * 4 + r;
            if (rr < NNODES) h0[(size_t)rr * HMID + c0 + t * 16 + m] = acc[t][r];
        }
    }
}

// ---------------- GCN aggregation ----------------
// self-loop + bias init: hagg[i] = h0[i] * dinv[i]^2 + b_gcn
__global__ void k_hagg_init(const float* __restrict__ h0, const float* __restrict__ dinv,
                            const float* __restrict__ bgcn, float* __restrict__ hagg) {
    int idx = blockIdx.x * 256 + threadIdx.x;  // N * 64 float4s
    if (idx >= NNODES * 64) return;
    int i = idx >> 6, c4 = idx & 63;
    float w = dinv[i]; w = w * w;
    float4 v = ((const float4*)h0)[(size_t)i * 64 + c4];
    float4 b = ((const float4*)bgcn)[c4];
    float4 o; o.x = v.x * w + b.x; o.y = v.y * w + b.y; o.z = v.z * w + b.z; o.w = v.w * w + b.w;
    ((float4*)hagg)[(size_t)i * 64 + c4] = o;
}

// one wave per edge, 64 lanes x float4 = 256 cols
__global__ void k_gcn_scatter(const int* __restrict__ src, const int* __restrict__ dst,
                              const float* __restrict__ h0, const float* __restrict__ dinv,
                              float* __restrict__ hagg) {
    int gid = blockIdx.x * 256 + threadIdx.x;
    int e = gid >> 6, lane = gid & 63;
    if (e >= EEDGES) return;
    int s = src[e], d = dst[e];
    float w = dinv[s] * dinv[d];
    float4 v = ((const float4*)h0)[(size_t)s * 64 + lane];
    float* o = hagg + (size_t)d * HMID + lane * 4;
    atomicAdd(o + 0, v.x * w);
    atomicAdd(o + 1, v.y * w);
    atomicAdd(o + 2, v.z * w);
    atomicAdd(o + 3, v.w * w);
}

// LeakyReLU + convert to bf16 for GEMM2 A-operand
__global__ void k_relu_cvt(const float* __restrict__ hagg, __bf16* __restrict__ hbf) {
    int idx = blockIdx.x * 256 + threadIdx.x;  // N*64 float4s
    if (idx >= NNODES * 64) return;
    float4 v = ((const float4*)hagg)[idx];
    bf16x4 o;
    o[0] = (__bf16)(v.x >= 0.f ? v.x : 0.01f * v.x);
    o[1] = (__bf16)(v.y >= 0.f ? v.y : 0.01f * v.y);
    o[2] = (__bf16)(v.z >= 0.f ? v.z : 0.01f * v.z);
    o[3] = (__bf16)(v.w >= 0.f ? v.w : 0.01f * v.w);
    ((bf16x4*)hbf)[idx] = o;
}

// ---------------- GEMM2: qkvs = h @ [Wq|Wk|Wv|Ws] + bias ----------------
// block = 4 waves -> 64 rows x 128 cols; grid (ceil(N/64), 512/128)
__global__ __launch_bounds__(256) void k_gemm2(const __bf16* __restrict__ hbf,
                                               const __bf16* __restrict__ Wallt,
                                               const float* __restrict__ ball,
                                               float* __restrict__ qkvs) {
    int lane = threadIdx.x & 63;
    int wave = threadIdx.x >> 6;
    int m = lane & 15;
    int q = lane >> 4;
    int r0 = blockIdx.x * 64 + wave * 16;
    int c0 = blockIdx.y * 128;
    int row = r0 + m; if (row > NNODES - 1) row = NNODES - 1;
    const __bf16* hp = hbf + (size_t)row * HMID + q * 8;
    f32x4 acc[8] = {};
#pragma unroll
    for (int k0 = 0; k0 < HMID; k0 += 32) {
        bf16x8 a = *(const bf16x8*)(hp + k0);
#pragma unroll
        for (int t = 0; t < 8; t++) {
            bf16x8 b = *(const bf16x8*)(Wallt + (size_t)(c0 + t * 16 + m) * HMID + k0 + q * 8);
            acc[t] = __builtin_amdgcn_mfma_f32_16x16x32_bf16(a, b, acc[t], 0, 0, 0);
        }
    }
#pragma unroll
    for (int t = 0; t < 8; t++) {
        float bias = ball[c0 + t * 16 + m];
#pragma unroll
        for (int r = 0; r < 4; r++) {
            int rr = r0 + q * 4 + r;
            if (rr < NNODES) qkvs[(size_t)rr * 512 + c0 + t * 16 + m] = acc[t][r] + bias;
        }
    }
}

// ---------------- attention score ----------------
// 32 lanes per edge: alpha_raw[e] = dot(q[dst], k[src]) / sqrt(DOUT); accumulate S1,S2
__global__ __launch_bounds__(256) void k_alpha(const int* __restrict__ src, const int* __restrict__ dst,
                                               const float* __restrict__ qkvs,
                                               float* __restrict__ alpha, float* __restrict__ S) {
    int tid = blockIdx.x * 256 + threadIdx.x;
    int l = threadIdx.x & 31;
    int slot = tid >> 5;
    int nslots = gridDim.x * 8;
    float s1 = 0.f, s2 = 0.f;
    for (int e = slot; e < EEDGES; e += nslots) {
        int sN = src[e], dN = dst[e];
        float4 qv = ((const float4*)(qkvs + (size_t)dN * 512))[l];         // q: cols 0..127
        float4 kv = ((const float4*)(qkvs + (size_t)sN * 512 + 128))[l];   // k: cols 128..255
        float d = qv.x * kv.x + qv.y * kv.y + qv.z * kv.z + qv.w * kv.w;
#pragma unroll
        for (int off = 16; off > 0; off >>= 1) d += __shfl_xor(d, off, 32);
        if (l == 0) {
            float a = d * 0.08838834764831845f;  // 1/sqrt(128)
            alpha[e] = a;
            s1 += a; s2 += a * a;
        }
    }
#pragma unroll
    for (int off = 32; off > 0; off >>= 1) {
        s1 += __shfl_xor(s1, off, 64);
        s2 += __shfl_xor(s2, off, 64);
    }
    __shared__ float sh[8];
    int wave = threadIdx.x >> 6;
    if ((threadIdx.x & 63) == 0) { sh[wave] = s1; sh[4 + wave] = s2; }
    __syncthreads();
    if (threadIdx.x == 0) {
        atomicAdd(&S[0], sh[0] + sh[1] + sh[2] + sh[3]);
        atomicAdd(&S[1], sh[4] + sh[5] + sh[6] + sh[7]);
    }
}

__global__ void k_stats(float* __restrict__ S) {
    float mean = S[0] / (float)EEDGES;
    float var = (S[1] - (float)EEDGES * mean * mean) / (float)(EEDGES - 1);
    float stdv = sqrtf(fmaxf(var, 1e-20f));
    S[2] = mean;
    S[3] = 3.0f / stdv;  // SCALE_PARAM / std (alpha/( (1/3) std ))
}

// ---------------- output ----------------
// out init = skip term s = qkvs cols 384..511
__global__ void k_out_init(const float* __restrict__ qkvs, float* __restrict__ out) {
    int idx = blockIdx.x * 256 + threadIdx.x;  // N * 32 float4s
    if (idx >= NNODES * 32) return;
    int i = idx >> 5, c4 = idx & 31;
    ((float4*)out)[(size_t)i * 32 + c4] = ((const float4*)(qkvs + (size_t)i * 512 + 384))[c4];
}

// 32 lanes per edge: out[dst] += v[src] * sigmoid((alpha-mean)*3/std)
__global__ void k_msg_scatter(const int* __restrict__ src, const int* __restrict__ dst,
                              const float* __restrict__ qkvs, const float* __restrict__ alpha,
                              const float* __restrict__ S, float* __restrict__ out) {
    int gid = blockIdx.x * 256 + threadIdx.x;
    int e = gid >> 5, l = gid & 31;
    if (e >= EEDGES) return;
    float mean = S[2], scl = S[3];
    float z = (alpha[e] - mean) * scl;
    float sg = 1.0f / (1.0f + __expf(-z));
    int s = src[e], d = dst[e];
    float4 v = ((const float4*)(qkvs + (size_t)s * 512 + 256))[l];  // v: cols 256..383
    float* o = out + (size_t)d * DOUT + l * 4;
    atomicAdd(o + 0, v.x * sg);
    atomicAdd(o + 1, v.y * sg);
    atomicAdd(o + 2, v.z * sg);
    atomicAdd(o + 3, v.w * sg);
}

// ---------------- launch ----------------
extern "C" void kernel_launch(void* const* d_in, const int* in_sizes, int n_in,
                              void* d_out, int out_size, void* d_ws, size_t ws_size,
                              hipStream_t stream) {
    const float* x  = (const float*)d_in[0];
    const int* ei   = (const int*)d_in[1];
    const int* srcI = ei;
    const int* dstI = ei + EEDGES;
    const float* Wg = (const float*)d_in[2];
    const float* bg = (const float*)d_in[3];
    const float* Wq = (const float*)d_in[4];  const float* bq = (const float*)d_in[5];
    const float* Wk = (const float*)d_in[6];  const float* bk = (const float*)d_in[7];
    const float* Wv = (const float*)d_in[8];  const float* bv = (const float*)d_in[9];
    const float* Ws = (const float*)d_in[10]; const float* bs = (const float*)d_in[11];
    float* out = (float*)d_out;

    char* wsb = (char*)d_ws;
    size_t off = 0;
    auto alloc = [&](size_t bytes) -> void* {
        void* p = wsb + off;
        off += (bytes + 255) & ~(size_t)255;
        return p;
    };
    float*  deg    = (float*)alloc((size_t)NNODES * 4);
    float*  dinv   = (float*)alloc((size_t)NNODES * 4);
    float*  S      = (float*)alloc(64);
    __bf16* Wt     = (__bf16*)alloc((size_t)HMID * FIN * 2);
    __bf16* Wallt  = (__bf16*)alloc((size_t)512 * HMID * 2);
    float*  ball   = (float*)alloc(512 * 4);
    float*  h0     = (float*)alloc((size_t)NNODES * HMID * 4);
    float*  hagg   = (float*)alloc((size_t)NNODES * HMID * 4);
    __bf16* hbf    = (__bf16*)alloc((size_t)NNODES * HMID * 2);
    float*  qkvs   = (float*)alloc((size_t)NNODES * 512 * 4);
    float*  alphab = (float*)alloc((size_t)EEDGES * 4);
    if (off > ws_size) return;  // fail loudly via wrong output rather than corrupt

    k_prep_wgcn<<<(FIN * HMID + 255) / 256, 256, 0, stream>>>(Wg, Wt);
    dim3 gw((HMID * DOUT + 255) / 256, 4);
    k_prep_watt<<<gw, 256, 0, stream>>>(Wq, Wk, Wv, Ws, bq, bk, bv, bs, Wallt, ball);

    k_deg_init<<<(NNODES + 255) / 256, 256, 0, stream>>>(deg, S);
    k_deg_acc<<<(EEDGES + 255) / 256, 256, 0, stream>>>(dstI, deg);
    k_dinv<<<(NNODES + 255) / 256, 256, 0, stream>>>(deg, dinv);

    dim3 g1((NNODES + 63) / 64, HMID / 128);
    k_gemm1<<<g1, 256, 0, stream>>>(x, Wt, h0);

    k_hagg_init<<<(NNODES * 64 + 255) / 256, 256, 0, stream>>>(h0, dinv, bg, hagg);
    k_gcn_scatter<<<EEDGES / 4, 256, 0, stream>>>(srcI, dstI, h0, dinv, hagg);
    k_relu_cvt<<<(NNODES * 64 + 255) / 256, 256, 0, stream>>>(hagg, hbf);

    dim3 g2((NNODES + 63) / 64, 512 / 128);
    k_gemm2<<<g2, 256, 0, stream>>>(hbf, Wallt, ball, qkvs);

    k_alpha<<<1024, 256, 0, stream>>>(srcI, dstI, qkvs, alphab, S);
    k_stats<<<1, 1, 0, stream>>>(S);

    k_out_init<<<(NNODES * 32 + 255) / 256, 256, 0, stream>>>(qkvs, out);
    k_msg_scatter<<<EEDGES / 8, 256, 0, stream>>>(srcI, dstI, qkvs, alphab, S, out);
}

// Round 2
// 502.677 us; speedup vs baseline: 4.0252x; 4.0252x over previous
//
#include <hip/hip_runtime.h>
#include <hip/hip_bf16.h>

#define NNODES 20000
#define EEDGES 320000
#define FIN 1024
#define HMID 256
#define DOUT 128

typedef __bf16 bf16x8 __attribute__((ext_vector_type(8)));
typedef __bf16 bf16x4 __attribute__((ext_vector_type(4)));
typedef float f32x4 __attribute__((ext_vector_type(4)));

// ---------------- weight prep ----------------
__global__ void k_prep_wgcn(const float* __restrict__ W, __bf16* __restrict__ Wt) {
    int tid = blockIdx.x * 256 + threadIdx.x;
    if (tid >= FIN * HMID) return;
    int k = tid >> 8;
    int n = tid & 255;
    Wt[(size_t)n * FIN + k] = (__bf16)W[tid];
}

__global__ void k_prep_watt(const float* __restrict__ Wq, const float* __restrict__ Wk,
                            const float* __restrict__ Wv, const float* __restrict__ Ws,
                            const float* __restrict__ bq, const float* __restrict__ bk,
                            const float* __restrict__ bv, const float* __restrict__ bs,
                            __bf16* __restrict__ Wallt, float* __restrict__ ball) {
    int g = blockIdx.y;
    const float* W = (g == 0) ? Wq : (g == 1) ? Wk : (g == 2) ? Wv : Ws;
    int tid = blockIdx.x * 256 + threadIdx.x;
    if (tid < HMID * DOUT) {
        int k = tid >> 7;
        int n = tid & 127;
        Wallt[(size_t)(g * DOUT + n) * HMID + k] = (__bf16)W[tid];
    }
    if (tid < DOUT) {
        const float* b = (g == 0) ? bq : (g == 1) ? bk : (g == 2) ? bv : bs;
        ball[g * DOUT + tid] = b[tid];
    }
}

// ---------------- CSR build (counting sort by dst) ----------------
__global__ void k_init(int* __restrict__ cnt, float* __restrict__ S) {
    int i = blockIdx.x * 256 + threadIdx.x;
    if (i < NNODES) cnt[i] = 0;
    if (i < 16) S[i] = 0.0f;
}

__global__ void k_count(const int* __restrict__ dst, int* __restrict__ cnt) {
    int e = blockIdx.x * 256 + threadIdx.x;
    if (e < EEDGES) atomicAdd(&cnt[dst[e]], 1);
}

// dinv from cnt (+1 self loop); zero cursors
__global__ void k_dinv(const int* __restrict__ cnt, float* __restrict__ dinv,
                       int* __restrict__ cursor) {
    int i = blockIdx.x * 256 + threadIdx.x;
    if (i < NNODES) {
        dinv[i] = rsqrtf((float)cnt[i] + 1.0f);
        cursor[i] = 0;
    }
}

// exclusive prefix sum of cnt -> rowptr, single block of 1024, 20 elems/thread
__global__ __launch_bounds__(1024) void k_scan(const int* __restrict__ cnt,
                                               int* __restrict__ rowptr) {
    __shared__ int sh[1024];
    int t = threadIdx.x;
    int base = t * 20;
    int local[20];
    int sum = 0;
#pragma unroll
    for (int j = 0; j < 20; j++) {
        int i = base + j;
        int v = (i < NNODES) ? cnt[i] : 0;
        local[j] = sum;
        sum += v;
    }
    sh[t] = sum;
    __syncthreads();
    for (int off = 1; off < 1024; off <<= 1) {
        int v = (t >= off) ? sh[t - off] : 0;
        __syncthreads();
        sh[t] += v;
        __syncthreads();
    }
    int prev = (t > 0) ? sh[t - 1] : 0;
#pragma unroll
    for (int j = 0; j < 20; j++) {
        int i = base + j;
        if (i < NNODES) rowptr[i] = prev + local[j];
    }
    if (t == 1023) rowptr[NNODES] = sh[1023];
}

__global__ void k_fill(const int* __restrict__ src, const int* __restrict__ dst,
                       const int* __restrict__ rowptr, int* __restrict__ cursor,
                       int* __restrict__ srcsorted, int* __restrict__ esorted) {
    int e = blockIdx.x * 256 + threadIdx.x;
    if (e >= EEDGES) return;
    int d = dst[e];
    int pos = atomicAdd(&cursor[d], 1);
    int w = rowptr[d] + pos;
    srcsorted[w] = src[e];
    esorted[w] = e;
}

// ---------------- GEMM1: h0 = x @ W_gcn ----------------
__global__ __launch_bounds__(256) void k_gemm1(const float* __restrict__ x,
                                               const __bf16* __restrict__ Wt,
                                               float* __restrict__ h0) {
    int lane = threadIdx.x & 63;
    int wave = threadIdx.x >> 6;
    int m = lane & 15;
    int q = lane >> 4;
    int r0 = blockIdx.x * 64 + wave * 16;
    int c0 = blockIdx.y * 128;
    int row = r0 + m; if (row > NNODES - 1) row = NNODES - 1;
    const float* xp = x + (size_t)row * FIN + q * 8;
    f32x4 acc[8] = {};
    for (int k0 = 0; k0 < FIN; k0 += 32) {
        const float4* ap = (const float4*)(xp + k0);
        float4 a0 = ap[0], a1 = ap[1];
        bf16x8 a;
        a[0] = (__bf16)a0.x; a[1] = (__bf16)a0.y; a[2] = (__bf16)a0.z; a[3] = (__bf16)a0.w;
        a[4] = (__bf16)a1.x; a[5] = (__bf16)a1.y; a[6] = (__bf16)a1.z; a[7] = (__bf16)a1.w;
#pragma unroll
        for (int t = 0; t < 8; t++) {
            bf16x8 b = *(const bf16x8*)(Wt + (size_t)(c0 + t * 16 + m) * FIN + k0 + q * 8);
            acc[t] = __builtin_amdgcn_mfma_f32_16x16x32_bf16(a, b, acc[t], 0, 0, 0);
        }
    }
#pragma unroll
    for (int t = 0; t < 8; t++) {
#pragma unroll
        for (int r = 0; r < 4; r++) {
            int rr = r0 + q * 4 + r;
            if (rr < NNODES) h0[(size_t)rr * HMID + c0 + t * 16 + m] = acc[t][r];
        }
    }
}

// ---------------- GCN gather: hbf[n] = bf16(LeakyReLU(self + sum + bias)) ----------------
// one wave per node, 64 lanes x float4 = 256 cols
__global__ __launch_bounds__(256) void k_gcn_gather(const int* __restrict__ rowptr,
                                                    const int* __restrict__ srcsorted,
                                                    const float* __restrict__ h0,
                                                    const float* __restrict__ dinv,
                                                    const float* __restrict__ bgcn,
                                                    __bf16* __restrict__ hbf) {
    int gid = blockIdx.x * 256 + threadIdx.x;
    int n = gid >> 6, l = gid & 63;
    if (n >= NNODES) return;
    float dn = dinv[n];
    float wn = dn * dn;
    float4 v = ((const float4*)h0)[(size_t)n * 64 + l];
    float4 b = ((const float4*)bgcn)[l];
    float ax = v.x * wn + b.x, ay = v.y * wn + b.y, az = v.z * wn + b.z, aw = v.w * wn + b.w;
    int beg = rowptr[n], end = rowptr[n + 1];
    int i = beg;
    for (; i + 1 < end; i += 2) {
        int s0 = srcsorted[i], s1 = srcsorted[i + 1];
        float w0 = dinv[s0] * dn, w1 = dinv[s1] * dn;
        float4 v0 = ((const float4*)h0)[(size_t)s0 * 64 + l];
        float4 v1 = ((const float4*)h0)[(size_t)s1 * 64 + l];
        ax += v0.x * w0 + v1.x * w1;
        ay += v0.y * w0 + v1.y * w1;
        az += v0.z * w0 + v1.z * w1;
        aw += v0.w * w0 + v1.w * w1;
    }
    if (i < end) {
        int s0 = srcsorted[i];
        float w0 = dinv[s0] * dn;
        float4 v0 = ((const float4*)h0)[(size_t)s0 * 64 + l];
        ax += v0.x * w0; ay += v0.y * w0; az += v0.z * w0; aw += v0.w * w0;
    }
    bf16x4 o;
    o[0] = (__bf16)(ax >= 0.f ? ax : 0.01f * ax);
    o[1] = (__bf16)(ay >= 0.f ? ay : 0.01f * ay);
    o[2] = (__bf16)(az >= 0.f ? az : 0.01f * az);
    o[3] = (__bf16)(aw >= 0.f ? aw : 0.01f * aw);
    ((bf16x4*)hbf)[(size_t)n * 64 + l] = o;
}

// ---------------- GEMM2: qkvs = h @ [Wq|Wk|Wv|Ws] + bias ----------------
__global__ __launch_bounds__(256) void k_gemm2(const __bf16* __restrict__ hbf,
                                               const __bf16* __restrict__ Wallt,
                                               const float* __restrict__ ball,
                                               float* __restrict__ qkvs) {
    int lane = threadIdx.x & 63;
    int wave = threadIdx.x >> 6;
    int m = lane & 15;
    int q = lane >> 4;
    int r0 = blockIdx.x * 64 + wave * 16;
    int c0 = blockIdx.y * 128;
    int row = r0 + m; if (row > NNODES - 1) row = NNODES - 1;
    const __bf16* hp = hbf + (size_t)row * HMID + q * 8;
    f32x4 acc[8] = {};
#pragma unroll
    for (int k0 = 0; k0 < HMID; k0 += 32) {
        bf16x8 a = *(const bf16x8*)(hp + k0);
#pragma unroll
        for (int t = 0; t < 8; t++) {
            bf16x8 b = *(const bf16x8*)(Wallt + (size_t)(c0 + t * 16 + m) * HMID + k0 + q * 8);
            acc[t] = __builtin_amdgcn_mfma_f32_16x16x32_bf16(a, b, acc[t], 0, 0, 0);
        }
    }
#pragma unroll
    for (int t = 0; t < 8; t++) {
        float bias = ball[c0 + t * 16 + m];
#pragma unroll
        for (int r = 0; r < 4; r++) {
            int rr = r0 + q * 4 + r;
            if (rr < NNODES) qkvs[(size_t)rr * 512 + c0 + t * 16 + m] = acc[t][r] + bias;
        }
    }
}

// ---------------- attention score ----------------
__global__ __launch_bounds__(256) void k_alpha(const int* __restrict__ src, const int* __restrict__ dst,
                                               const float* __restrict__ qkvs,
                                               float* __restrict__ alpha, float* __restrict__ S) {
    int tid = blockIdx.x * 256 + threadIdx.x;
    int l = threadIdx.x & 31;
    int slot = tid >> 5;
    int nslots = gridDim.x * 8;
    float s1 = 0.f, s2 = 0.f;
    for (int e = slot; e < EEDGES; e += nslots) {
        int sN = src[e], dN = dst[e];
        float4 qv = ((const float4*)(qkvs + (size_t)dN * 512))[l];
        float4 kv = ((const float4*)(qkvs + (size_t)sN * 512 + 128))[l];
        float d = qv.x * kv.x + qv.y * kv.y + qv.z * kv.z + qv.w * kv.w;
#pragma unroll
        for (int off = 16; off > 0; off >>= 1) d += __shfl_xor(d, off, 32);
        if (l == 0) {
            float a = d * 0.08838834764831845f;  // 1/sqrt(128)
            alpha[e] = a;
            s1 += a; s2 += a * a;
        }
    }
#pragma unroll
    for (int off = 32; off > 0; off >>= 1) {
        s1 += __shfl_xor(s1, off, 64);
        s2 += __shfl_xor(s2, off, 64);
    }
    __shared__ float sh[8];
    int wave = threadIdx.x >> 6;
    if ((threadIdx.x & 63) == 0) { sh[wave] = s1; sh[4 + wave] = s2; }
    __syncthreads();
    if (threadIdx.x == 0) {
        atomicAdd(&S[0], sh[0] + sh[1] + sh[2] + sh[3]);
        atomicAdd(&S[1], sh[4] + sh[5] + sh[6] + sh[7]);
    }
}

__global__ void k_stats(float* __restrict__ S) {
    float mean = S[0] / (float)EEDGES;
    float var = (S[1] - (float)EEDGES * mean * mean) / (float)(EEDGES - 1);
    float stdv = sqrtf(fmaxf(var, 1e-20f));
    S[2] = mean;
    S[3] = 3.0f / stdv;
}

// ---------------- output gather: out[n] = skip + sum sigmoid(z_e) * v[src] ----------------
// one wave per node, 64 lanes x float2 = 128 cols
__global__ __launch_bounds__(256) void k_msg_gather(const int* __restrict__ rowptr,
                                                    const int* __restrict__ srcsorted,
                                                    const int* __restrict__ esorted,
                                                    const float* __restrict__ qkvs,
                                                    const float* __restrict__ alpha,
                                                    const float* __restrict__ S,
                                                    float* __restrict__ out) {
    int gid = blockIdx.x * 256 + threadIdx.x;
    int n = gid >> 6, l = gid & 63;
    if (n >= NNODES) return;
    float mean = S[2], scl = S[3];
    float2 acc = ((const float2*)(qkvs + (size_t)n * 512 + 384))[l];  // skip: s-cols
    int beg = rowptr[n], end = rowptr[n + 1];
    int i = beg;
    for (; i + 1 < end; i += 2) {
        int s0 = srcsorted[i], s1 = srcsorted[i + 1];
        int e0 = esorted[i], e1 = esorted[i + 1];
        float z0 = (alpha[e0] - mean) * scl;
        float z1 = (alpha[e1] - mean) * scl;
        float g0 = 1.0f / (1.0f + __expf(-z0));
        float g1 = 1.0f / (1.0f + __expf(-z1));
        float2 v0 = ((const float2*)(qkvs + (size_t)s0 * 512 + 256))[l];
        float2 v1 = ((const float2*)(qkvs + (size_t)s1 * 512 + 256))[l];
        acc.x += v0.x * g0 + v1.x * g1;
        acc.y += v0.y * g0 + v1.y * g1;
    }
    if (i < end) {
        int s0 = srcsorted[i];
        int e0 = esorted[i];
        float z0 = (alpha[e0] - mean) * scl;
        float g0 = 1.0f / (1.0f + __expf(-z0));
        float2 v0 = ((const float2*)(qkvs + (size_t)s0 * 512 + 256))[l];
        acc.x += v0.x * g0;
        acc.y += v0.y * g0;
    }
    ((float2*)(out + (size_t)n * DOUT))[l] = acc;
}

// ---------------- launch ----------------
extern "C" void kernel_launch(void* const* d_in, const int* in_sizes, int n_in,
                              void* d_out, int out_size, void* d_ws, size_t ws_size,
                              hipStream_t stream) {
    const float* x  = (const float*)d_in[0];
    const int* ei   = (const int*)d_in[1];
    const int* srcI = ei;
    const int* dstI = ei + EEDGES;
    const float* Wg = (const float*)d_in[2];
    const float* bg = (const float*)d_in[3];
    const float* Wq = (const float*)d_in[4];  const float* bq = (const float*)d_in[5];
    const float* Wk = (const float*)d_in[6];  const float* bk = (const float*)d_in[7];
    const float* Wv = (const float*)d_in[8];  const float* bv = (const float*)d_in[9];
    const float* Ws = (const float*)d_in[10]; const float* bs = (const float*)d_in[11];
    float* out = (float*)d_out;

    char* wsb = (char*)d_ws;
    size_t off = 0;
    auto alloc = [&](size_t bytes) -> void* {
        void* p = wsb + off;
        off += (bytes + 255) & ~(size_t)255;
        return p;
    };
    int*    cnt    = (int*)alloc((size_t)NNODES * 4);
    int*    rowptr = (int*)alloc((size_t)(NNODES + 1) * 4);
    int*    cursor = (int*)alloc((size_t)NNODES * 4);
    int*    srcst  = (int*)alloc((size_t)EEDGES * 4);
    int*    esort  = (int*)alloc((size_t)EEDGES * 4);
    float*  dinv   = (float*)alloc((size_t)NNODES * 4);
    float*  S      = (float*)alloc(64);
    __bf16* Wt     = (__bf16*)alloc((size_t)HMID * FIN * 2);
    __bf16* Wallt  = (__bf16*)alloc((size_t)512 * HMID * 2);
    float*  ball   = (float*)alloc(512 * 4);
    float*  h0     = (float*)alloc((size_t)NNODES * HMID * 4);
    __bf16* hbf    = (__bf16*)alloc((size_t)NNODES * HMID * 2);
    float*  qkvs   = (float*)alloc((size_t)NNODES * 512 * 4);
    float*  alphab = (float*)alloc((size_t)EEDGES * 4);
    if (off > ws_size) return;

    // weight prep (independent of graph work)
    k_prep_wgcn<<<(FIN * HMID + 255) / 256, 256, 0, stream>>>(Wg, Wt);
    dim3 gw((HMID * DOUT + 255) / 256, 4);
    k_prep_watt<<<gw, 256, 0, stream>>>(Wq, Wk, Wv, Ws, bq, bk, bv, bs, Wallt, ball);

    // CSR build
    k_init<<<(NNODES + 255) / 256, 256, 0, stream>>>(cnt, S);
    k_count<<<(EEDGES + 255) / 256, 256, 0, stream>>>(dstI, cnt);
    k_dinv<<<(NNODES + 255) / 256, 256, 0, stream>>>(cnt, dinv, cursor);
    k_scan<<<1, 1024, 0, stream>>>(cnt, rowptr);
    k_fill<<<(EEDGES + 255) / 256, 256, 0, stream>>>(srcI, dstI, rowptr, cursor, srcst, esort);

    // GEMM1
    dim3 g1((NNODES + 63) / 64, HMID / 128);
    k_gemm1<<<g1, 256, 0, stream>>>(x, Wt, h0);

    // GCN aggregate (gather) + LeakyReLU + bf16
    k_gcn_gather<<<(NNODES * 64 + 255) / 256, 256, 0, stream>>>(rowptr, srcst, h0, dinv, bg, hbf);

    // GEMM2
    dim3 g2((NNODES + 63) / 64, 512 / 128);
    k_gemm2<<<g2, 256, 0, stream>>>(hbf, Wallt, ball, qkvs);

    // attention scores + stats
    k_alpha<<<1024, 256, 0, stream>>>(srcI, dstI, qkvs, alphab, S);
    k_stats<<<1, 1, 0, stream>>>(S);

    // output gather (fused skip init)
    k_msg_gather<<<(NNODES * 64 + 255) / 256, 256, 0, stream>>>(rowptr, srcst, esort, qkvs, alphab, S, out);
}

// Round 3
// 462.681 us; speedup vs baseline: 4.3731x; 1.0864x over previous
//
#include <hip/hip_runtime.h>
#include <hip/hip_bf16.h>

#define NNODES 20000
#define EEDGES 320000
#define FIN 1024
#define HMID 256
#define DOUT 128

typedef __bf16 bf16x8 __attribute__((ext_vector_type(8)));
typedef __bf16 bf16x4 __attribute__((ext_vector_type(4)));
typedef __bf16 bf16x2 __attribute__((ext_vector_type(2)));
typedef float f32x4 __attribute__((ext_vector_type(4)));

typedef const __attribute__((address_space(1))) void* gas_ptr;
typedef __attribute__((address_space(3))) void* las_ptr;
__device__ __forceinline__ void async_copy16(const void* g, void* l) {
    __builtin_amdgcn_global_load_lds((gas_ptr)g, (las_ptr)l, 16, 0, 0);
}

// ---------------- weight prep ----------------
__global__ void k_prep_wgcn(const float* __restrict__ W, __bf16* __restrict__ Wt) {
    int tid = blockIdx.x * 256 + threadIdx.x;
    if (tid >= FIN * HMID) return;
    int k = tid >> 8;
    int n = tid & 255;
    Wt[(size_t)n * FIN + k] = (__bf16)W[tid];
}

__global__ void k_prep_watt(const float* __restrict__ Wq, const float* __restrict__ Wk,
                            const float* __restrict__ Wv, const float* __restrict__ Ws,
                            const float* __restrict__ bq, const float* __restrict__ bk,
                            const float* __restrict__ bv, const float* __restrict__ bs,
                            __bf16* __restrict__ Wallt, float* __restrict__ ball) {
    int g = blockIdx.y;
    const float* W = (g == 0) ? Wq : (g == 1) ? Wk : (g == 2) ? Wv : Ws;
    int tid = blockIdx.x * 256 + threadIdx.x;
    if (tid < HMID * DOUT) {
        int k = tid >> 7;
        int n = tid & 127;
        Wallt[(size_t)(g * DOUT + n) * HMID + k] = (__bf16)W[tid];
    }
    if (tid < DOUT) {
        const float* b = (g == 0) ? bq : (g == 1) ? bk : (g == 2) ? bv : bs;
        ball[g * DOUT + tid] = b[tid];
    }
}

// ---------------- CSR build ----------------
__global__ void k_init(int* __restrict__ cnt, float* __restrict__ S) {
    int i = blockIdx.x * 256 + threadIdx.x;
    if (i < NNODES) cnt[i] = 0;
    if (i < 16) S[i] = 0.0f;
}

__global__ void k_count(const int* __restrict__ dst, int* __restrict__ cnt) {
    int e = blockIdx.x * 256 + threadIdx.x;
    if (e < EEDGES) atomicAdd(&cnt[dst[e]], 1);
}

__global__ void k_dinv(const int* __restrict__ cnt, float* __restrict__ dinv,
                       int* __restrict__ cursor) {
    int i = blockIdx.x * 256 + threadIdx.x;
    if (i < NNODES) {
        dinv[i] = rsqrtf((float)cnt[i] + 1.0f);
        cursor[i] = 0;
    }
}

__global__ __launch_bounds__(1024) void k_scan(const int* __restrict__ cnt,
                                               int* __restrict__ rowptr) {
    __shared__ int sh[1024];
    int t = threadIdx.x;
    int base = t * 20;
    int local[20];
    int sum = 0;
#pragma unroll
    for (int j = 0; j < 20; j++) {
        int i = base + j;
        int v = (i < NNODES) ? cnt[i] : 0;
        local[j] = sum;
        sum += v;
    }
    sh[t] = sum;
    __syncthreads();
    for (int off = 1; off < 1024; off <<= 1) {
        int v = (t >= off) ? sh[t - off] : 0;
        __syncthreads();
        sh[t] += v;
        __syncthreads();
    }
    int prev = (t > 0) ? sh[t - 1] : 0;
#pragma unroll
    for (int j = 0; j < 20; j++) {
        int i = base + j;
        if (i < NNODES) rowptr[i] = prev + local[j];
    }
    if (t == 1023) rowptr[NNODES] = sh[1023];
}

__global__ void k_fill(const int* __restrict__ src, const int* __restrict__ dst,
                       const int* __restrict__ rowptr, int* __restrict__ cursor,
                       int* __restrict__ srcsorted) {
    int e = blockIdx.x * 256 + threadIdx.x;
    if (e >= EEDGES) return;
    int d = dst[e];
    int pos = atomicAdd(&cursor[d], 1);
    srcsorted[rowptr[d] + pos] = src[e];
}

// ---------------- GEMM1: h0bf = bf16(x @ W_gcn) ----------------
// 128x128 tile, 4 waves, LDS staged via global_load_lds.
// As: [8 chunk16B][128 row] fp32 (chunk c = k c*4..c*4+4). Bs: [4 chunk][128 col] bf16.
__global__ __launch_bounds__(256) void k_gemm1(const float* __restrict__ x,
                                               const __bf16* __restrict__ Wt,
                                               __bf16* __restrict__ h0bf) {
    __shared__ float As[4096];     // 16 KB
    __shared__ __bf16 Bs[4096];    // 8 KB
    int t = threadIdx.x;
    int lane = t & 63;
    int m = lane & 15, q = lane >> 4;
    int wave = t >> 6;
    int wr = (wave & 1) * 64;
    int wc = (wave >> 1) * 64;
    int r0 = blockIdx.x * 128;
    int c0 = blockIdx.y * 128;

    // staging source pointers (fixed per thread; k0 added in loop)
    const float* asrc[4];
    float* aldst[4];
#pragma unroll
    for (int j = 0; j < 4; j++) {
        int u = j * 256 + t;
        int row = r0 + (u & 127);
        if (row >= NNODES) row = NNODES - 1;
        asrc[j] = x + (size_t)row * FIN + (u >> 7) * 4;
        aldst[j] = &As[(size_t)u * 4];
    }
    const __bf16* bsrc[2];
    __bf16* bldst[2];
#pragma unroll
    for (int j = 0; j < 2; j++) {
        int u = j * 256 + t;
        bsrc[j] = Wt + (size_t)(c0 + (u & 127)) * FIN + (u >> 7) * 8;
        bldst[j] = &Bs[(size_t)u * 8];
    }

    f32x4 acc[4][4] = {};

    for (int k0 = 0; k0 < FIN; k0 += 32) {
#pragma unroll
        for (int j = 0; j < 4; j++) async_copy16(asrc[j] + k0, aldst[j]);
#pragma unroll
        for (int j = 0; j < 2; j++) async_copy16(bsrc[j] + k0, bldst[j]);
        __syncthreads();

        bf16x8 af[4], bfr[4];
#pragma unroll
        for (int i = 0; i < 4; i++) {
            int R = wr + i * 16 + m;
            f32x4 a0 = *(const f32x4*)&As[(size_t)((2 * q) * 128 + R) * 4];
            f32x4 a1 = *(const f32x4*)&As[(size_t)((2 * q + 1) * 128 + R) * 4];
            bf16x8 a;
            a[0] = (__bf16)a0[0]; a[1] = (__bf16)a0[1]; a[2] = (__bf16)a0[2]; a[3] = (__bf16)a0[3];
            a[4] = (__bf16)a1[0]; a[5] = (__bf16)a1[1]; a[6] = (__bf16)a1[2]; a[7] = (__bf16)a1[3];
            af[i] = a;
        }
#pragma unroll
        for (int jb = 0; jb < 4; jb++) {
            int C = wc + jb * 16 + m;
            bfr[jb] = *(const bf16x8*)&Bs[(size_t)(q * 128 + C) * 8];
        }
#pragma unroll
        for (int i = 0; i < 4; i++)
#pragma unroll
            for (int jb = 0; jb < 4; jb++)
                acc[i][jb] = __builtin_amdgcn_mfma_f32_16x16x32_bf16(af[i], bfr[jb], acc[i][jb], 0, 0, 0);
        __syncthreads();
    }

#pragma unroll
    for (int i = 0; i < 4; i++)
#pragma unroll
        for (int jb = 0; jb < 4; jb++)
#pragma unroll
            for (int r = 0; r < 4; r++) {
                int row = r0 + wr + i * 16 + q * 4 + r;
                int col = c0 + wc + jb * 16 + m;
                if (row < NNODES) h0bf[(size_t)row * 256 + col] = (__bf16)acc[i][jb][r];
            }
}

// ---------------- GCN gather: hbf = bf16(LeakyReLU(self + sum + bias)) ----------------
__global__ __launch_bounds__(256) void k_gcn_gather(const int* __restrict__ rowptr,
                                                    const int* __restrict__ srcsorted,
                                                    const __bf16* __restrict__ h0bf,
                                                    const float* __restrict__ dinv,
                                                    const float* __restrict__ bgcn,
                                                    __bf16* __restrict__ hbf) {
    int gid = blockIdx.x * 256 + threadIdx.x;
    int n = gid >> 6, l = gid & 63;
    if (n >= NNODES) return;
    float dn = dinv[n];
    float wn = dn * dn;
    bf16x4 hv = *(const bf16x4*)(h0bf + (size_t)n * 256 + l * 4);
    float4 b = ((const float4*)bgcn)[l];
    float ax = (float)hv[0] * wn + b.x;
    float ay = (float)hv[1] * wn + b.y;
    float az = (float)hv[2] * wn + b.z;
    float aw = (float)hv[3] * wn + b.w;
    int beg = rowptr[n], end = rowptr[n + 1];
    int i = beg;
    for (; i + 1 < end; i += 2) {
        int s0 = srcsorted[i], s1 = srcsorted[i + 1];
        float w0 = dinv[s0] * dn, w1 = dinv[s1] * dn;
        bf16x4 v0 = *(const bf16x4*)(h0bf + (size_t)s0 * 256 + l * 4);
        bf16x4 v1 = *(const bf16x4*)(h0bf + (size_t)s1 * 256 + l * 4);
        ax += (float)v0[0] * w0 + (float)v1[0] * w1;
        ay += (float)v0[1] * w0 + (float)v1[1] * w1;
        az += (float)v0[2] * w0 + (float)v1[2] * w1;
        aw += (float)v0[3] * w0 + (float)v1[3] * w1;
    }
    if (i < end) {
        int s0 = srcsorted[i];
        float w0 = dinv[s0] * dn;
        bf16x4 v0 = *(const bf16x4*)(h0bf + (size_t)s0 * 256 + l * 4);
        ax += (float)v0[0] * w0; ay += (float)v0[1] * w0;
        az += (float)v0[2] * w0; aw += (float)v0[3] * w0;
    }
    bf16x4 o;
    o[0] = (__bf16)(ax >= 0.f ? ax : 0.01f * ax);
    o[1] = (__bf16)(ay >= 0.f ? ay : 0.01f * ay);
    o[2] = (__bf16)(az >= 0.f ? az : 0.01f * az);
    o[3] = (__bf16)(aw >= 0.f ? aw : 0.01f * aw);
    *(bf16x4*)(hbf + (size_t)n * 256 + l * 4) = o;
}

// ---------------- GEMM2: [q|k|v|s] = hbf @ Wallt + ball, bf16 out ----------------
// y-block 0,1 -> qkbf cols 0..255 ; y-block 2,3 -> vsbf cols 0..255
__global__ __launch_bounds__(256) void k_gemm2(const __bf16* __restrict__ hbf,
                                               const __bf16* __restrict__ Wallt,
                                               const float* __restrict__ ball,
                                               __bf16* __restrict__ qkbf,
                                               __bf16* __restrict__ vsbf) {
    __shared__ __bf16 As[4096];   // [4 chunk][128 row] 8 KB
    __shared__ __bf16 Bs[4096];   // [4 chunk][128 col] 8 KB
    int t = threadIdx.x;
    int lane = t & 63;
    int m = lane & 15, q = lane >> 4;
    int wave = t >> 6;
    int wr = (wave & 1) * 64;
    int wc = (wave >> 1) * 64;
    int r0 = blockIdx.x * 128;
    int c0 = blockIdx.y * 128;

    const __bf16* asrc[2];
    __bf16* aldst[2];
#pragma unroll
    for (int j = 0; j < 2; j++) {
        int u = j * 256 + t;
        int row = r0 + (u & 127);
        if (row >= NNODES) row = NNODES - 1;
        asrc[j] = hbf + (size_t)row * HMID + (u >> 7) * 8;
        aldst[j] = &As[(size_t)u * 8];
    }
    const __bf16* bsrc[2];
    __bf16* bldst[2];
#pragma unroll
    for (int j = 0; j < 2; j++) {
        int u = j * 256 + t;
        bsrc[j] = Wallt + (size_t)(c0 + (u & 127)) * HMID + (u >> 7) * 8;
        bldst[j] = &Bs[(size_t)u * 8];
    }

    f32x4 acc[4][4] = {};

    for (int k0 = 0; k0 < HMID; k0 += 32) {
#pragma unroll
        for (int j = 0; j < 2; j++) async_copy16(asrc[j] + k0, aldst[j]);
#pragma unroll
        for (int j = 0; j < 2; j++) async_copy16(bsrc[j] + k0, bldst[j]);
        __syncthreads();

        bf16x8 af[4], bfr[4];
#pragma unroll
        for (int i = 0; i < 4; i++) af[i] = *(const bf16x8*)&As[(size_t)(q * 128 + wr + i * 16 + m) * 8];
#pragma unroll
        for (int jb = 0; jb < 4; jb++) bfr[jb] = *(const bf16x8*)&Bs[(size_t)(q * 128 + wc + jb * 16 + m) * 8];
#pragma unroll
        for (int i = 0; i < 4; i++)
#pragma unroll
            for (int jb = 0; jb < 4; jb++)
                acc[i][jb] = __builtin_amdgcn_mfma_f32_16x16x32_bf16(af[i], bfr[jb], acc[i][jb], 0, 0, 0);
        __syncthreads();
    }

#pragma unroll
    for (int jb = 0; jb < 4; jb++) {
        int gcol = c0 + wc + jb * 16 + m;
        float bias = ball[gcol];
        __bf16* dstbuf = (gcol < 256) ? qkbf : vsbf;
        int dcol = gcol & 255;
#pragma unroll
        for (int i = 0; i < 4; i++)
#pragma unroll
            for (int r = 0; r < 4; r++) {
                int row = r0 + wr + i * 16 + q * 4 + r;
                if (row < NNODES) dstbuf[(size_t)row * 256 + dcol] = (__bf16)(acc[i][jb][r] + bias);
            }
    }
}

// ---------------- attention scores (CSR order, q in registers) ----------------
// one wave per node; 4 groups of 16 lanes process 4 edges in flight
__global__ __launch_bounds__(256) void k_alpha(const int* __restrict__ rowptr,
                                               const int* __restrict__ srcsorted,
                                               const __bf16* __restrict__ qkbf,
                                               float* __restrict__ alpha, float* __restrict__ S) {
    int n = (blockIdx.x * 256 + threadIdx.x) >> 6;
    int lane = threadIdx.x & 63;
    int g = lane >> 4, l = lane & 15;
    float s1 = 0.f, s2 = 0.f;
    if (n < NNODES) {
        bf16x8 qb = *(const bf16x8*)(qkbf + (size_t)n * 256 + l * 8);
        float qf[8];
#pragma unroll
        for (int j = 0; j < 8; j++) qf[j] = (float)qb[j];
        int beg = rowptr[n], end = rowptr[n + 1];
        for (int i = beg + g; i < end; i += 4) {
            int s = srcsorted[i];
            bf16x8 kb = *(const bf16x8*)(qkbf + (size_t)s * 256 + 128 + l * 8);
            float d = 0.f;
#pragma unroll
            for (int j = 0; j < 8; j++) d += qf[j] * (float)kb[j];
#pragma unroll
            for (int off = 1; off < 16; off <<= 1) d += __shfl_xor(d, off, 64);
            if (l == 0) {
                float a = d * 0.08838834764831845f;  // 1/sqrt(128)
                alpha[i] = a;
                s1 += a; s2 += a * a;
            }
        }
    }
#pragma unroll
    for (int off = 1; off < 64; off <<= 1) {
        s1 += __shfl_xor(s1, off, 64);
        s2 += __shfl_xor(s2, off, 64);
    }
    __shared__ float sh[8];
    int wave = threadIdx.x >> 6;
    if ((threadIdx.x & 63) == 0) { sh[wave] = s1; sh[4 + wave] = s2; }
    __syncthreads();
    if (threadIdx.x == 0) {
        atomicAdd(&S[0], sh[0] + sh[1] + sh[2] + sh[3]);
        atomicAdd(&S[1], sh[4] + sh[5] + sh[6] + sh[7]);
    }
}

__global__ void k_stats(float* __restrict__ S) {
    float mean = S[0] / (float)EEDGES;
    float var = (S[1] - (float)EEDGES * mean * mean) / (float)(EEDGES - 1);
    float stdv = sqrtf(fmaxf(var, 1e-20f));
    S[2] = mean;
    S[3] = 3.0f / stdv;
}

// ---------------- output gather ----------------
// one wave per node; v = vsbf cols 0..127, skip s = vsbf cols 128..255
__global__ __launch_bounds__(256) void k_msg_gather(const int* __restrict__ rowptr,
                                                    const int* __restrict__ srcsorted,
                                                    const __bf16* __restrict__ vsbf,
                                                    const float* __restrict__ alpha,
                                                    const float* __restrict__ S,
                                                    float* __restrict__ out) {
    int n = (blockIdx.x * 256 + threadIdx.x) >> 6;
    int l = threadIdx.x & 63;
    if (n >= NNODES) return;
    float mean = S[2], scl = S[3];
    bf16x2 sb = *(const bf16x2*)(vsbf + (size_t)n * 256 + 128 + l * 2);
    float ax = (float)sb[0], ay = (float)sb[1];
    int beg = rowptr[n], end = rowptr[n + 1];
    int i = beg;
    for (; i + 1 < end; i += 2) {
        int s0 = srcsorted[i], s1 = srcsorted[i + 1];
        float z0 = (alpha[i] - mean) * scl;
        float z1 = (alpha[i + 1] - mean) * scl;
        float g0 = 1.0f / (1.0f + __expf(-z0));
        float g1 = 1.0f / (1.0f + __expf(-z1));
        bf16x2 v0 = *(const bf16x2*)(vsbf + (size_t)s0 * 256 + l * 2);
        bf16x2 v1 = *(const bf16x2*)(vsbf + (size_t)s1 * 256 + l * 2);
        ax += (float)v0[0] * g0 + (float)v1[0] * g1;
        ay += (float)v0[1] * g0 + (float)v1[1] * g1;
    }
    if (i < end) {
        int s0 = srcsorted[i];
        float z0 = (alpha[i] - mean) * scl;
        float g0 = 1.0f / (1.0f + __expf(-z0));
        bf16x2 v0 = *(const bf16x2*)(vsbf + (size_t)s0 * 256 + l * 2);
        ax += (float)v0[0] * g0;
        ay += (float)v0[1] * g0;
    }
    float2 o; o.x = ax; o.y = ay;
    ((float2*)(out + (size_t)n * DOUT))[l] = o;
}

// ---------------- launch ----------------
extern "C" void kernel_launch(void* const* d_in, const int* in_sizes, int n_in,
                              void* d_out, int out_size, void* d_ws, size_t ws_size,
                              hipStream_t stream) {
    const float* x  = (const float*)d_in[0];
    const int* ei   = (const int*)d_in[1];
    const int* srcI = ei;
    const int* dstI = ei + EEDGES;
    const float* Wg = (const float*)d_in[2];
    const float* bg = (const float*)d_in[3];
    const float* Wq = (const float*)d_in[4];  const float* bq = (const float*)d_in[5];
    const float* Wk = (const float*)d_in[6];  const float* bk = (const float*)d_in[7];
    const float* Wv = (const float*)d_in[8];  const float* bv = (const float*)d_in[9];
    const float* Ws = (const float*)d_in[10]; const float* bs = (const float*)d_in[11];
    float* out = (float*)d_out;

    char* wsb = (char*)d_ws;
    size_t off = 0;
    auto alloc = [&](size_t bytes) -> void* {
        void* p = wsb + off;
        off += (bytes + 255) & ~(size_t)255;
        return p;
    };
    int*    cnt    = (int*)alloc((size_t)NNODES * 4);
    int*    rowptr = (int*)alloc((size_t)(NNODES + 1) * 4);
    int*    cursor = (int*)alloc((size_t)NNODES * 4);
    int*    srcst  = (int*)alloc((size_t)EEDGES * 4);
    float*  dinv   = (float*)alloc((size_t)NNODES * 4);
    float*  S      = (float*)alloc(64);
    __bf16* Wt     = (__bf16*)alloc((size_t)HMID * FIN * 2);
    __bf16* Wallt  = (__bf16*)alloc((size_t)512 * HMID * 2);
    float*  ball   = (float*)alloc(512 * 4);
    __bf16* h0bf   = (__bf16*)alloc((size_t)NNODES * HMID * 2);
    __bf16* hbf    = (__bf16*)alloc((size_t)NNODES * HMID * 2);
    __bf16* qkbf   = (__bf16*)alloc((size_t)NNODES * 256 * 2);
    __bf16* vsbf   = (__bf16*)alloc((size_t)NNODES * 256 * 2);
    float*  alphab = (float*)alloc((size_t)EEDGES * 4);
    if (off > ws_size) return;

    k_prep_wgcn<<<(FIN * HMID + 255) / 256, 256, 0, stream>>>(Wg, Wt);
    dim3 gw((HMID * DOUT + 255) / 256, 4);
    k_prep_watt<<<gw, 256, 0, stream>>>(Wq, Wk, Wv, Ws, bq, bk, bv, bs, Wallt, ball);

    k_init<<<(NNODES + 255) / 256, 256, 0, stream>>>(cnt, S);
    k_count<<<(EEDGES + 255) / 256, 256, 0, stream>>>(dstI, cnt);
    k_dinv<<<(NNODES + 255) / 256, 256, 0, stream>>>(cnt, dinv, cursor);
    k_scan<<<1, 1024, 0, stream>>>(cnt, rowptr);
    k_fill<<<(EEDGES + 255) / 256, 256, 0, stream>>>(srcI, dstI, rowptr, cursor, srcst);

    dim3 g1((NNODES + 127) / 128, HMID / 128);
    k_gemm1<<<g1, 256, 0, stream>>>(x, Wt, h0bf);

    k_gcn_gather<<<(NNODES * 64 + 255) / 256, 256, 0, stream>>>(rowptr, srcst, h0bf, dinv, bg, hbf);

    dim3 g2((NNODES + 127) / 128, 512 / 128);
    k_gemm2<<<g2, 256, 0, stream>>>(hbf, Wallt, ball, qkbf, vsbf);

    k_alpha<<<(NNODES + 3) / 4, 256, 0, stream>>>(rowptr, srcst, qkbf, alphab, S);
    k_stats<<<1, 1, 0, stream>>>(S);

    k_msg_gather<<<(NNODES * 64 + 255) / 256, 256, 0, stream>>>(rowptr, srcst, vsbf, alphab, S, out);
}

// Round 4
// 455.000 us; speedup vs baseline: 4.4469x; 1.0169x over previous
//
#include <hip/hip_runtime.h>
#include <hip/hip_bf16.h>

#define NNODES 20000
#define EEDGES 320000
#define FIN 1024
#define HMID 256
#define DOUT 128

typedef __bf16 bf16x8 __attribute__((ext_vector_type(8)));
typedef __bf16 bf16x4 __attribute__((ext_vector_type(4)));
typedef __bf16 bf16x2 __attribute__((ext_vector_type(2)));
typedef float f32x4 __attribute__((ext_vector_type(4)));

typedef const __attribute__((address_space(1))) void* gas_ptr;
typedef __attribute__((address_space(3))) void* las_ptr;
__device__ __forceinline__ void async_copy16(const void* g, void* l) {
    __builtin_amdgcn_global_load_lds((gas_ptr)g, (las_ptr)l, 16, 0, 0);
}

// ---------------- weight prep ----------------
__global__ void k_prep_wgcn(const float* __restrict__ W, __bf16* __restrict__ Wt) {
    int tid = blockIdx.x * 256 + threadIdx.x;
    if (tid >= FIN * HMID) return;
    int k = tid >> 8;
    int n = tid & 255;
    Wt[(size_t)n * FIN + k] = (__bf16)W[tid];
}

__global__ void k_prep_watt(const float* __restrict__ Wq, const float* __restrict__ Wk,
                            const float* __restrict__ Wv, const float* __restrict__ Ws,
                            const float* __restrict__ bq, const float* __restrict__ bk,
                            const float* __restrict__ bv, const float* __restrict__ bs,
                            __bf16* __restrict__ Wallt, float* __restrict__ ball) {
    int g = blockIdx.y;
    const float* W = (g == 0) ? Wq : (g == 1) ? Wk : (g == 2) ? Wv : Ws;
    int tid = blockIdx.x * 256 + threadIdx.x;
    if (tid < HMID * DOUT) {
        int k = tid >> 7;
        int n = tid & 127;
        Wallt[(size_t)(g * DOUT + n) * HMID + k] = (__bf16)W[tid];
    }
    if (tid < DOUT) {
        const float* b = (g == 0) ? bq : (g == 1) ? bk : (g == 2) ? bv : bs;
        ball[g * DOUT + tid] = b[tid];
    }
}

// ---------------- CSR build ----------------
__global__ void k_init(int* __restrict__ cnt, float* __restrict__ S) {
    int i = blockIdx.x * 256 + threadIdx.x;
    if (i < NNODES) cnt[i] = 0;
    if (i < 16) S[i] = 0.0f;
}

__global__ void k_count(const int* __restrict__ dst, int* __restrict__ cnt) {
    int e = blockIdx.x * 256 + threadIdx.x;
    if (e < EEDGES) atomicAdd(&cnt[dst[e]], 1);
}

__global__ void k_dinv(const int* __restrict__ cnt, float* __restrict__ dinv,
                       int* __restrict__ cursor) {
    int i = blockIdx.x * 256 + threadIdx.x;
    if (i < NNODES) {
        dinv[i] = rsqrtf((float)cnt[i] + 1.0f);
        cursor[i] = 0;
    }
}

__global__ __launch_bounds__(1024) void k_scan(const int* __restrict__ cnt,
                                               int* __restrict__ rowptr) {
    __shared__ int sh[1024];
    int t = threadIdx.x;
    int base = t * 20;
    int local[20];
    int sum = 0;
#pragma unroll
    for (int j = 0; j < 20; j++) {
        int i = base + j;
        int v = (i < NNODES) ? cnt[i] : 0;
        local[j] = sum;
        sum += v;
    }
    sh[t] = sum;
    __syncthreads();
    for (int off = 1; off < 1024; off <<= 1) {
        int v = (t >= off) ? sh[t - off] : 0;
        __syncthreads();
        sh[t] += v;
        __syncthreads();
    }
    int prev = (t > 0) ? sh[t - 1] : 0;
#pragma unroll
    for (int j = 0; j < 20; j++) {
        int i = base + j;
        if (i < NNODES) rowptr[i] = prev + local[j];
    }
    if (t == 1023) rowptr[NNODES] = sh[1023];
}

// also pre-gathers dinv[src] into sorted order (kills dependent-load chain later)
__global__ void k_fill(const int* __restrict__ src, const int* __restrict__ dst,
                       const int* __restrict__ rowptr, int* __restrict__ cursor,
                       const float* __restrict__ dinv,
                       int* __restrict__ srcsorted, float* __restrict__ wsorted) {
    int e = blockIdx.x * 256 + threadIdx.x;
    if (e >= EEDGES) return;
    int d = dst[e];
    int s = src[e];
    int pos = atomicAdd(&cursor[d], 1);
    int w = rowptr[d] + pos;
    srcsorted[w] = s;
    wsorted[w] = dinv[s];
}

// ---------------- GEMM1: h0bf = bf16(x @ W_gcn) ----------------
__global__ __launch_bounds__(256) void k_gemm1(const float* __restrict__ x,
                                               const __bf16* __restrict__ Wt,
                                               __bf16* __restrict__ h0bf) {
    __shared__ float As[4096];
    __shared__ __bf16 Bs[4096];
    int t = threadIdx.x;
    int lane = t & 63;
    int m = lane & 15, q = lane >> 4;
    int wave = t >> 6;
    int wr = (wave & 1) * 64;
    int wc = (wave >> 1) * 64;
    int r0 = blockIdx.x * 128;
    int c0 = blockIdx.y * 128;

    const float* asrc[4];
    float* aldst[4];
#pragma unroll
    for (int j = 0; j < 4; j++) {
        int u = j * 256 + t;
        int row = r0 + (u & 127);
        if (row >= NNODES) row = NNODES - 1;
        asrc[j] = x + (size_t)row * FIN + (u >> 7) * 4;
        aldst[j] = &As[(size_t)u * 4];
    }
    const __bf16* bsrc[2];
    __bf16* bldst[2];
#pragma unroll
    for (int j = 0; j < 2; j++) {
        int u = j * 256 + t;
        bsrc[j] = Wt + (size_t)(c0 + (u & 127)) * FIN + (u >> 7) * 8;
        bldst[j] = &Bs[(size_t)u * 8];
    }

    f32x4 acc[4][4] = {};

    for (int k0 = 0; k0 < FIN; k0 += 32) {
#pragma unroll
        for (int j = 0; j < 4; j++) async_copy16(asrc[j] + k0, aldst[j]);
#pragma unroll
        for (int j = 0; j < 2; j++) async_copy16(bsrc[j] + k0, bldst[j]);
        __syncthreads();

        bf16x8 af[4], bfr[4];
#pragma unroll
        for (int i = 0; i < 4; i++) {
            int R = wr + i * 16 + m;
            f32x4 a0 = *(const f32x4*)&As[(size_t)((2 * q) * 128 + R) * 4];
            f32x4 a1 = *(const f32x4*)&As[(size_t)((2 * q + 1) * 128 + R) * 4];
            bf16x8 a;
            a[0] = (__bf16)a0[0]; a[1] = (__bf16)a0[1]; a[2] = (__bf16)a0[2]; a[3] = (__bf16)a0[3];
            a[4] = (__bf16)a1[0]; a[5] = (__bf16)a1[1]; a[6] = (__bf16)a1[2]; a[7] = (__bf16)a1[3];
            af[i] = a;
        }
#pragma unroll
        for (int jb = 0; jb < 4; jb++) {
            int C = wc + jb * 16 + m;
            bfr[jb] = *(const bf16x8*)&Bs[(size_t)(q * 128 + C) * 8];
        }
#pragma unroll
        for (int i = 0; i < 4; i++)
#pragma unroll
            for (int jb = 0; jb < 4; jb++)
                acc[i][jb] = __builtin_amdgcn_mfma_f32_16x16x32_bf16(af[i], bfr[jb], acc[i][jb], 0, 0, 0);
        __syncthreads();
    }

#pragma unroll
    for (int i = 0; i < 4; i++)
#pragma unroll
        for (int jb = 0; jb < 4; jb++)
#pragma unroll
            for (int r = 0; r < 4; r++) {
                int row = r0 + wr + i * 16 + q * 4 + r;
                int col = c0 + wc + jb * 16 + m;
                if (row < NNODES) h0bf[(size_t)row * 256 + col] = (__bf16)acc[i][jb][r];
            }
}

// ---------------- GCN gather (batch-4 MLP) ----------------
__global__ __launch_bounds__(256) void k_gcn_gather(const int* __restrict__ rowptr,
                                                    const int* __restrict__ srcsorted,
                                                    const float* __restrict__ wsorted,
                                                    const __bf16* __restrict__ h0bf,
                                                    const float* __restrict__ dinv,
                                                    const float* __restrict__ bgcn,
                                                    __bf16* __restrict__ hbf) {
    int gid = blockIdx.x * 256 + threadIdx.x;
    int n = gid >> 6, l = gid & 63;
    if (n >= NNODES) return;
    float dn = dinv[n];
    float wn = dn * dn;
    bf16x4 hv = *(const bf16x4*)(h0bf + (size_t)n * 256 + l * 4);
    float4 b = ((const float4*)bgcn)[l];
    float ax = (float)hv[0] * wn + b.x;
    float ay = (float)hv[1] * wn + b.y;
    float az = (float)hv[2] * wn + b.z;
    float aw = (float)hv[3] * wn + b.w;
    int beg = rowptr[n], end = rowptr[n + 1];
    for (int i = beg; i < end; i += 4) {
        int i1 = i + 1 < end ? i + 1 : end - 1;
        int i2 = i + 2 < end ? i + 2 : end - 1;
        int i3 = i + 3 < end ? i + 3 : end - 1;
        int s0 = srcsorted[i], s1 = srcsorted[i1], s2 = srcsorted[i2], s3 = srcsorted[i3];
        float w0 = wsorted[i] * dn;
        float w1 = (i + 1 < end) ? wsorted[i1] * dn : 0.f;
        float w2 = (i + 2 < end) ? wsorted[i2] * dn : 0.f;
        float w3 = (i + 3 < end) ? wsorted[i3] * dn : 0.f;
        bf16x4 v0 = *(const bf16x4*)(h0bf + (size_t)s0 * 256 + l * 4);
        bf16x4 v1 = *(const bf16x4*)(h0bf + (size_t)s1 * 256 + l * 4);
        bf16x4 v2 = *(const bf16x4*)(h0bf + (size_t)s2 * 256 + l * 4);
        bf16x4 v3 = *(const bf16x4*)(h0bf + (size_t)s3 * 256 + l * 4);
        ax += (float)v0[0] * w0 + (float)v1[0] * w1 + (float)v2[0] * w2 + (float)v3[0] * w3;
        ay += (float)v0[1] * w0 + (float)v1[1] * w1 + (float)v2[1] * w2 + (float)v3[1] * w3;
        az += (float)v0[2] * w0 + (float)v1[2] * w1 + (float)v2[2] * w2 + (float)v3[2] * w3;
        aw += (float)v0[3] * w0 + (float)v1[3] * w1 + (float)v2[3] * w2 + (float)v3[3] * w3;
    }
    bf16x4 o;
    o[0] = (__bf16)(ax >= 0.f ? ax : 0.01f * ax);
    o[1] = (__bf16)(ay >= 0.f ? ay : 0.01f * ay);
    o[2] = (__bf16)(az >= 0.f ? az : 0.01f * az);
    o[3] = (__bf16)(aw >= 0.f ? aw : 0.01f * aw);
    *(bf16x4*)(hbf + (size_t)n * 256 + l * 4) = o;
}

// ---------------- GEMM2: q/k/v/s tables = hbf @ Wallt + ball ----------------
// blockIdx.y selects output table (0=q,1=k,2=v,3=s), each N x 128 bf16
__global__ __launch_bounds__(256) void k_gemm2(const __bf16* __restrict__ hbf,
                                               const __bf16* __restrict__ Wallt,
                                               const float* __restrict__ ball,
                                               __bf16* __restrict__ qarr,
                                               __bf16* __restrict__ karr,
                                               __bf16* __restrict__ varr,
                                               __bf16* __restrict__ sarr) {
    __shared__ __bf16 As[4096];
    __shared__ __bf16 Bs[4096];
    int t = threadIdx.x;
    int lane = t & 63;
    int m = lane & 15, q = lane >> 4;
    int wave = t >> 6;
    int wr = (wave & 1) * 64;
    int wc = (wave >> 1) * 64;
    int r0 = blockIdx.x * 128;
    int c0 = blockIdx.y * 128;
    __bf16* tbl = (blockIdx.y == 0) ? qarr : (blockIdx.y == 1) ? karr
                : (blockIdx.y == 2) ? varr : sarr;

    const __bf16* asrc[2];
    __bf16* aldst[2];
#pragma unroll
    for (int j = 0; j < 2; j++) {
        int u = j * 256 + t;
        int row = r0 + (u & 127);
        if (row >= NNODES) row = NNODES - 1;
        asrc[j] = hbf + (size_t)row * HMID + (u >> 7) * 8;
        aldst[j] = &As[(size_t)u * 8];
    }
    const __bf16* bsrc[2];
    __bf16* bldst[2];
#pragma unroll
    for (int j = 0; j < 2; j++) {
        int u = j * 256 + t;
        bsrc[j] = Wallt + (size_t)(c0 + (u & 127)) * HMID + (u >> 7) * 8;
        bldst[j] = &Bs[(size_t)u * 8];
    }

    f32x4 acc[4][4] = {};

    for (int k0 = 0; k0 < HMID; k0 += 32) {
#pragma unroll
        for (int j = 0; j < 2; j++) async_copy16(asrc[j] + k0, aldst[j]);
#pragma unroll
        for (int j = 0; j < 2; j++) async_copy16(bsrc[j] + k0, bldst[j]);
        __syncthreads();

        bf16x8 af[4], bfr[4];
#pragma unroll
        for (int i = 0; i < 4; i++) af[i] = *(const bf16x8*)&As[(size_t)(q * 128 + wr + i * 16 + m) * 8];
#pragma unroll
        for (int jb = 0; jb < 4; jb++) bfr[jb] = *(const bf16x8*)&Bs[(size_t)(q * 128 + wc + jb * 16 + m) * 8];
#pragma unroll
        for (int i = 0; i < 4; i++)
#pragma unroll
            for (int jb = 0; jb < 4; jb++)
                acc[i][jb] = __builtin_amdgcn_mfma_f32_16x16x32_bf16(af[i], bfr[jb], acc[i][jb], 0, 0, 0);
        __syncthreads();
    }

#pragma unroll
    for (int jb = 0; jb < 4; jb++) {
        int dcol = wc + jb * 16 + m;          // 0..127 within table
        float bias = ball[c0 + dcol];
#pragma unroll
        for (int i = 0; i < 4; i++)
#pragma unroll
            for (int r = 0; r < 4; r++) {
                int row = r0 + wr + i * 16 + q * 4 + r;
                if (row < NNODES) tbl[(size_t)row * 128 + dcol] = (__bf16)(acc[i][jb][r] + bias);
            }
    }
}

// ---------------- attention scores (CSR order, q in regs, batch-4 per group) ----------------
__global__ __launch_bounds__(256) void k_alpha(const int* __restrict__ rowptr,
                                               const int* __restrict__ srcsorted,
                                               const __bf16* __restrict__ qarr,
                                               const __bf16* __restrict__ karr,
                                               float* __restrict__ alpha, float* __restrict__ S) {
    int n = (blockIdx.x * 256 + threadIdx.x) >> 6;
    int lane = threadIdx.x & 63;
    int g = lane >> 4, l = lane & 15;
    float s1 = 0.f, s2 = 0.f;
    if (n < NNODES) {
        bf16x8 qb = *(const bf16x8*)(qarr + (size_t)n * 128 + l * 8);
        float qf[8];
#pragma unroll
        for (int j = 0; j < 8; j++) qf[j] = (float)qb[j];
        int beg = rowptr[n], end = rowptr[n + 1];
        for (int i = beg + g; i < end; i += 16) {
            int i1 = i + 4 < end ? i + 4 : end - 1;
            int i2 = i + 8 < end ? i + 8 : end - 1;
            int i3 = i + 12 < end ? i + 12 : end - 1;
            int s0 = srcsorted[i], sA = srcsorted[i1], sB = srcsorted[i2], sC = srcsorted[i3];
            bf16x8 k0 = *(const bf16x8*)(karr + (size_t)s0 * 128 + l * 8);
            bf16x8 k1 = *(const bf16x8*)(karr + (size_t)sA * 128 + l * 8);
            bf16x8 k2 = *(const bf16x8*)(karr + (size_t)sB * 128 + l * 8);
            bf16x8 k3 = *(const bf16x8*)(karr + (size_t)sC * 128 + l * 8);
            float d0 = 0.f, d1 = 0.f, d2 = 0.f, d3 = 0.f;
#pragma unroll
            for (int j = 0; j < 8; j++) {
                d0 += qf[j] * (float)k0[j];
                d1 += qf[j] * (float)k1[j];
                d2 += qf[j] * (float)k2[j];
                d3 += qf[j] * (float)k3[j];
            }
#pragma unroll
            for (int off = 1; off < 16; off <<= 1) {
                d0 += __shfl_xor(d0, off, 64);
                d1 += __shfl_xor(d1, off, 64);
                d2 += __shfl_xor(d2, off, 64);
                d3 += __shfl_xor(d3, off, 64);
            }
            if (l == 0) {
                const float sc = 0.08838834764831845f;  // 1/sqrt(128)
                float a0 = d0 * sc;
                alpha[i] = a0; s1 += a0; s2 += a0 * a0;
                if (i + 4 < end)  { float a = d1 * sc; alpha[i + 4]  = a; s1 += a; s2 += a * a; }
                if (i + 8 < end)  { float a = d2 * sc; alpha[i + 8]  = a; s1 += a; s2 += a * a; }
                if (i + 12 < end) { float a = d3 * sc; alpha[i + 12] = a; s1 += a; s2 += a * a; }
            }
        }
    }
#pragma unroll
    for (int off = 1; off < 64; off <<= 1) {
        s1 += __shfl_xor(s1, off, 64);
        s2 += __shfl_xor(s2, off, 64);
    }
    __shared__ float sh[8];
    int wave = threadIdx.x >> 6;
    if ((threadIdx.x & 63) == 0) { sh[wave] = s1; sh[4 + wave] = s2; }
    __syncthreads();
    if (threadIdx.x == 0) {
        atomicAdd(&S[0], sh[0] + sh[1] + sh[2] + sh[3]);
        atomicAdd(&S[1], sh[4] + sh[5] + sh[6] + sh[7]);
    }
}

__global__ void k_stats(float* __restrict__ S) {
    float mean = S[0] / (float)EEDGES;
    float var = (S[1] - (float)EEDGES * mean * mean) / (float)(EEDGES - 1);
    float stdv = sqrtf(fmaxf(var, 1e-20f));
    S[2] = mean;
    S[3] = 3.0f / stdv;
}

// ---------------- output gather (batch-4 MLP) ----------------
__global__ __launch_bounds__(256) void k_msg_gather(const int* __restrict__ rowptr,
                                                    const int* __restrict__ srcsorted,
                                                    const __bf16* __restrict__ varr,
                                                    const __bf16* __restrict__ sarr,
                                                    const float* __restrict__ alpha,
                                                    const float* __restrict__ S,
                                                    float* __restrict__ out) {
    int n = (blockIdx.x * 256 + threadIdx.x) >> 6;
    int l = threadIdx.x & 63;
    if (n >= NNODES) return;
    float mean = S[2], scl = S[3];
    bf16x2 sb = *(const bf16x2*)(sarr + (size_t)n * 128 + l * 2);
    float ax = (float)sb[0], ay = (float)sb[1];
    int beg = rowptr[n], end = rowptr[n + 1];
    for (int i = beg; i < end; i += 4) {
        int i1 = i + 1 < end ? i + 1 : end - 1;
        int i2 = i + 2 < end ? i + 2 : end - 1;
        int i3 = i + 3 < end ? i + 3 : end - 1;
        int s0 = srcsorted[i], s1 = srcsorted[i1], s2 = srcsorted[i2], s3 = srcsorted[i3];
        float z0 = (alpha[i] - mean) * scl;
        float z1 = (alpha[i1] - mean) * scl;
        float z2 = (alpha[i2] - mean) * scl;
        float z3 = (alpha[i3] - mean) * scl;
        float g0 = 1.0f / (1.0f + __expf(-z0));
        float g1 = (i + 1 < end) ? 1.0f / (1.0f + __expf(-z1)) : 0.f;
        float g2 = (i + 2 < end) ? 1.0f / (1.0f + __expf(-z2)) : 0.f;
        float g3 = (i + 3 < end) ? 1.0f / (1.0f + __expf(-z3)) : 0.f;
        bf16x2 v0 = *(const bf16x2*)(varr + (size_t)s0 * 128 + l * 2);
        bf16x2 v1 = *(const bf16x2*)(varr + (size_t)s1 * 128 + l * 2);
        bf16x2 v2 = *(const bf16x2*)(varr + (size_t)s2 * 128 + l * 2);
        bf16x2 v3 = *(const bf16x2*)(varr + (size_t)s3 * 128 + l * 2);
        ax += (float)v0[0] * g0 + (float)v1[0] * g1 + (float)v2[0] * g2 + (float)v3[0] * g3;
        ay += (float)v0[1] * g0 + (float)v1[1] * g1 + (float)v2[1] * g2 + (float)v3[1] * g3;
    }
    float2 o; o.x = ax; o.y = ay;
    ((float2*)(out + (size_t)n * DOUT))[l] = o;
}

// ---------------- launch ----------------
extern "C" void kernel_launch(void* const* d_in, const int* in_sizes, int n_in,
                              void* d_out, int out_size, void* d_ws, size_t ws_size,
                              hipStream_t stream) {
    const float* x  = (const float*)d_in[0];
    const int* ei   = (const int*)d_in[1];
    const int* srcI = ei;
    const int* dstI = ei + EEDGES;
    const float* Wg = (const float*)d_in[2];
    const float* bg = (const float*)d_in[3];
    const float* Wq = (const float*)d_in[4];  const float* bq = (const float*)d_in[5];
    const float* Wk = (const float*)d_in[6];  const float* bk = (const float*)d_in[7];
    const float* Wv = (const float*)d_in[8];  const float* bv = (const float*)d_in[9];
    const float* Ws = (const float*)d_in[10]; const float* bs = (const float*)d_in[11];
    float* out = (float*)d_out;

    char* wsb = (char*)d_ws;
    size_t off = 0;
    auto alloc = [&](size_t bytes) -> void* {
        void* p = wsb + off;
        off += (bytes + 255) & ~(size_t)255;
        return p;
    };
    int*    cnt    = (int*)alloc((size_t)NNODES * 4);
    int*    rowptr = (int*)alloc((size_t)(NNODES + 1) * 4);
    int*    cursor = (int*)alloc((size_t)NNODES * 4);
    int*    srcst  = (int*)alloc((size_t)EEDGES * 4);
    float*  wsort  = (float*)alloc((size_t)EEDGES * 4);
    float*  dinv   = (float*)alloc((size_t)NNODES * 4);
    float*  S      = (float*)alloc(64);
    __bf16* Wt     = (__bf16*)alloc((size_t)HMID * FIN * 2);
    __bf16* Wallt  = (__bf16*)alloc((size_t)512 * HMID * 2);
    float*  ball   = (float*)alloc(512 * 4);
    __bf16* h0bf   = (__bf16*)alloc((size_t)NNODES * HMID * 2);
    __bf16* hbf    = (__bf16*)alloc((size_t)NNODES * HMID * 2);
    __bf16* qarr   = (__bf16*)alloc((size_t)NNODES * 128 * 2);
    __bf16* karr   = (__bf16*)alloc((size_t)NNODES * 128 * 2);
    __bf16* varr   = (__bf16*)alloc((size_t)NNODES * 128 * 2);
    __bf16* sarr   = (__bf16*)alloc((size_t)NNODES * 128 * 2);
    float*  alphab = (float*)alloc((size_t)EEDGES * 4);
    if (off > ws_size) return;

    k_prep_wgcn<<<(FIN * HMID + 255) / 256, 256, 0, stream>>>(Wg, Wt);
    dim3 gw((HMID * DOUT + 255) / 256, 4);
    k_prep_watt<<<gw, 256, 0, stream>>>(Wq, Wk, Wv, Ws, bq, bk, bv, bs, Wallt, ball);

    k_init<<<(NNODES + 255) / 256, 256, 0, stream>>>(cnt, S);
    k_count<<<(EEDGES + 255) / 256, 256, 0, stream>>>(dstI, cnt);
    k_dinv<<<(NNODES + 255) / 256, 256, 0, stream>>>(cnt, dinv, cursor);
    k_scan<<<1, 1024, 0, stream>>>(cnt, rowptr);
    k_fill<<<(EEDGES + 255) / 256, 256, 0, stream>>>(srcI, dstI, rowptr, cursor, dinv, srcst, wsort);

    dim3 g1((NNODES + 127) / 128, HMID / 128);
    k_gemm1<<<g1, 256, 0, stream>>>(x, Wt, h0bf);

    k_gcn_gather<<<(NNODES * 64 + 255) / 256, 256, 0, stream>>>(rowptr, srcst, wsort, h0bf, dinv, bg, hbf);

    dim3 g2((NNODES + 127) / 128, 4);
    k_gemm2<<<g2, 256, 0, stream>>>(hbf, Wallt, ball, qarr, karr, varr, sarr);

    k_alpha<<<(NNODES + 3) / 4, 256, 0, stream>>>(rowptr, srcst, qarr, karr, alphab, S);
    k_stats<<<1, 1, 0, stream>>>(S);

    k_msg_gather<<<(NNODES * 64 + 255) / 256, 256, 0, stream>>>(rowptr, srcst, varr, sarr, alphab, S, out);
}

// Round 5
// 339.060 us; speedup vs baseline: 5.9675x; 1.3419x over previous
//
#include <hip/hip_runtime.h>
#include <hip/hip_bf16.h>

#define NNODES 20000
#define EEDGES 320000
#define FIN 1024
#define HMID 256
#define DOUT 128
#define ALPHA_BLOCKS ((NNODES + 3) / 4)

typedef __bf16 bf16x8 __attribute__((ext_vector_type(8)));
typedef __bf16 bf16x4 __attribute__((ext_vector_type(4)));
typedef __bf16 bf16x2 __attribute__((ext_vector_type(2)));
typedef float f32x4 __attribute__((ext_vector_type(4)));

typedef const __attribute__((address_space(1))) void* gas_ptr;
typedef __attribute__((address_space(3))) void* las_ptr;
__device__ __forceinline__ void async_copy16(const void* g, void* l) {
    __builtin_amdgcn_global_load_lds((gas_ptr)g, (las_ptr)l, 16, 0, 0);
}

// ---------------- weight prep ----------------
__global__ void k_prep_wgcn(const float* __restrict__ W, __bf16* __restrict__ Wt) {
    int tid = blockIdx.x * 256 + threadIdx.x;
    if (tid >= FIN * HMID) return;
    int k = tid >> 8;
    int n = tid & 255;
    Wt[(size_t)n * FIN + k] = (__bf16)W[tid];
}

__global__ void k_prep_watt(const float* __restrict__ Wq, const float* __restrict__ Wk,
                            const float* __restrict__ Wv, const float* __restrict__ Ws,
                            const float* __restrict__ bq, const float* __restrict__ bk,
                            const float* __restrict__ bv, const float* __restrict__ bs,
                            __bf16* __restrict__ Wallt, float* __restrict__ ball) {
    int g = blockIdx.y;
    const float* W = (g == 0) ? Wq : (g == 1) ? Wk : (g == 2) ? Wv : Ws;
    int tid = blockIdx.x * 256 + threadIdx.x;
    if (tid < HMID * DOUT) {
        int k = tid >> 7;
        int n = tid & 127;
        Wallt[(size_t)(g * DOUT + n) * HMID + k] = (__bf16)W[tid];
    }
    if (tid < DOUT) {
        const float* b = (g == 0) ? bq : (g == 1) ? bk : (g == 2) ? bv : bs;
        ball[g * DOUT + tid] = b[tid];
    }
}

// ---------------- CSR build ----------------
__global__ void k_init(int* __restrict__ cnt, float* __restrict__ S) {
    int i = blockIdx.x * 256 + threadIdx.x;
    if (i < NNODES) cnt[i] = 0;
    if (i < 16) S[i] = 0.0f;
}

__global__ void k_count(const int* __restrict__ dst, int* __restrict__ cnt) {
    int e = blockIdx.x * 256 + threadIdx.x;
    if (e < EEDGES) atomicAdd(&cnt[dst[e]], 1);
}

__global__ void k_dinv(const int* __restrict__ cnt, float* __restrict__ dinv,
                       int* __restrict__ cursor) {
    int i = blockIdx.x * 256 + threadIdx.x;
    if (i < NNODES) {
        dinv[i] = rsqrtf((float)cnt[i] + 1.0f);
        cursor[i] = 0;
    }
}

__global__ __launch_bounds__(1024) void k_scan(const int* __restrict__ cnt,
                                               int* __restrict__ rowptr) {
    __shared__ int sh[1024];
    int t = threadIdx.x;
    int base = t * 20;
    int local[20];
    int sum = 0;
#pragma unroll
    for (int j = 0; j < 20; j++) {
        int i = base + j;
        int v = (i < NNODES) ? cnt[i] : 0;
        local[j] = sum;
        sum += v;
    }
    sh[t] = sum;
    __syncthreads();
    for (int off = 1; off < 1024; off <<= 1) {
        int v = (t >= off) ? sh[t - off] : 0;
        __syncthreads();
        sh[t] += v;
        __syncthreads();
    }
    int prev = (t > 0) ? sh[t - 1] : 0;
#pragma unroll
    for (int j = 0; j < 20; j++) {
        int i = base + j;
        if (i < NNODES) rowptr[i] = prev + local[j];
    }
    if (t == 1023) rowptr[NNODES] = sh[1023];
}

__global__ void k_fill(const int* __restrict__ src, const int* __restrict__ dst,
                       const int* __restrict__ rowptr, int* __restrict__ cursor,
                       const float* __restrict__ dinv,
                       int* __restrict__ srcsorted, float* __restrict__ wsorted) {
    int e = blockIdx.x * 256 + threadIdx.x;
    if (e >= EEDGES) return;
    int d = dst[e];
    int s = src[e];
    int pos = atomicAdd(&cursor[d], 1);
    int w = rowptr[d] + pos;
    srcsorted[w] = s;
    wsorted[w] = dinv[s];
}

// ---------------- GEMM1: h0bf = bf16(x @ W_gcn) ----------------
__global__ __launch_bounds__(256) void k_gemm1(const float* __restrict__ x,
                                               const __bf16* __restrict__ Wt,
                                               __bf16* __restrict__ h0bf) {
    __shared__ float As[4096];
    __shared__ __bf16 Bs[4096];
    int t = threadIdx.x;
    int lane = t & 63;
    int m = lane & 15, q = lane >> 4;
    int wave = t >> 6;
    int wr = (wave & 1) * 64;
    int wc = (wave >> 1) * 64;
    int r0 = blockIdx.x * 128;
    int c0 = blockIdx.y * 128;

    const float* asrc[4];
    float* aldst[4];
#pragma unroll
    for (int j = 0; j < 4; j++) {
        int u = j * 256 + t;
        int row = r0 + (u & 127);
        if (row >= NNODES) row = NNODES - 1;
        asrc[j] = x + (size_t)row * FIN + (u >> 7) * 4;
        aldst[j] = &As[(size_t)u * 4];
    }
    const __bf16* bsrc[2];
    __bf16* bldst[2];
#pragma unroll
    for (int j = 0; j < 2; j++) {
        int u = j * 256 + t;
        bsrc[j] = Wt + (size_t)(c0 + (u & 127)) * FIN + (u >> 7) * 8;
        bldst[j] = &Bs[(size_t)u * 8];
    }

    f32x4 acc[4][4] = {};

    for (int k0 = 0; k0 < FIN; k0 += 32) {
#pragma unroll
        for (int j = 0; j < 4; j++) async_copy16(asrc[j] + k0, aldst[j]);
#pragma unroll
        for (int j = 0; j < 2; j++) async_copy16(bsrc[j] + k0, bldst[j]);
        __syncthreads();

        bf16x8 af[4], bfr[4];
#pragma unroll
        for (int i = 0; i < 4; i++) {
            int R = wr + i * 16 + m;
            f32x4 a0 = *(const f32x4*)&As[(size_t)((2 * q) * 128 + R) * 4];
            f32x4 a1 = *(const f32x4*)&As[(size_t)((2 * q + 1) * 128 + R) * 4];
            bf16x8 a;
            a[0] = (__bf16)a0[0]; a[1] = (__bf16)a0[1]; a[2] = (__bf16)a0[2]; a[3] = (__bf16)a0[3];
            a[4] = (__bf16)a1[0]; a[5] = (__bf16)a1[1]; a[6] = (__bf16)a1[2]; a[7] = (__bf16)a1[3];
            af[i] = a;
        }
#pragma unroll
        for (int jb = 0; jb < 4; jb++) {
            int C = wc + jb * 16 + m;
            bfr[jb] = *(const bf16x8*)&Bs[(size_t)(q * 128 + C) * 8];
        }
#pragma unroll
        for (int i = 0; i < 4; i++)
#pragma unroll
            for (int jb = 0; jb < 4; jb++)
                acc[i][jb] = __builtin_amdgcn_mfma_f32_16x16x32_bf16(af[i], bfr[jb], acc[i][jb], 0, 0, 0);
        __syncthreads();
    }

#pragma unroll
    for (int i = 0; i < 4; i++)
#pragma unroll
        for (int jb = 0; jb < 4; jb++)
#pragma unroll
            for (int r = 0; r < 4; r++) {
                int row = r0 + wr + i * 16 + q * 4 + r;
                int col = c0 + wc + jb * 16 + m;
                if (row < NNODES) h0bf[(size_t)row * 256 + col] = (__bf16)acc[i][jb][r];
            }
}

// ---------------- GCN gather (batch-4 MLP) ----------------
__global__ __launch_bounds__(256) void k_gcn_gather(const int* __restrict__ rowptr,
                                                    const int* __restrict__ srcsorted,
                                                    const float* __restrict__ wsorted,
                                                    const __bf16* __restrict__ h0bf,
                                                    const float* __restrict__ dinv,
                                                    const float* __restrict__ bgcn,
                                                    __bf16* __restrict__ hbf) {
    int gid = blockIdx.x * 256 + threadIdx.x;
    int n = gid >> 6, l = gid & 63;
    if (n >= NNODES) return;
    float dn = dinv[n];
    float wn = dn * dn;
    bf16x4 hv = *(const bf16x4*)(h0bf + (size_t)n * 256 + l * 4);
    float4 b = ((const float4*)bgcn)[l];
    float ax = (float)hv[0] * wn + b.x;
    float ay = (float)hv[1] * wn + b.y;
    float az = (float)hv[2] * wn + b.z;
    float aw = (float)hv[3] * wn + b.w;
    int beg = rowptr[n], end = rowptr[n + 1];
    for (int i = beg; i < end; i += 4) {
        int i1 = i + 1 < end ? i + 1 : end - 1;
        int i2 = i + 2 < end ? i + 2 : end - 1;
        int i3 = i + 3 < end ? i + 3 : end - 1;
        int s0 = srcsorted[i], s1 = srcsorted[i1], s2 = srcsorted[i2], s3 = srcsorted[i3];
        float w0 = wsorted[i] * dn;
        float w1 = (i + 1 < end) ? wsorted[i1] * dn : 0.f;
        float w2 = (i + 2 < end) ? wsorted[i2] * dn : 0.f;
        float w3 = (i + 3 < end) ? wsorted[i3] * dn : 0.f;
        bf16x4 v0 = *(const bf16x4*)(h0bf + (size_t)s0 * 256 + l * 4);
        bf16x4 v1 = *(const bf16x4*)(h0bf + (size_t)s1 * 256 + l * 4);
        bf16x4 v2 = *(const bf16x4*)(h0bf + (size_t)s2 * 256 + l * 4);
        bf16x4 v3 = *(const bf16x4*)(h0bf + (size_t)s3 * 256 + l * 4);
        ax += (float)v0[0] * w0 + (float)v1[0] * w1 + (float)v2[0] * w2 + (float)v3[0] * w3;
        ay += (float)v0[1] * w0 + (float)v1[1] * w1 + (float)v2[1] * w2 + (float)v3[1] * w3;
        az += (float)v0[2] * w0 + (float)v1[2] * w1 + (float)v2[2] * w2 + (float)v3[2] * w3;
        aw += (float)v0[3] * w0 + (float)v1[3] * w1 + (float)v2[3] * w2 + (float)v3[3] * w3;
    }
    bf16x4 o;
    o[0] = (__bf16)(ax >= 0.f ? ax : 0.01f * ax);
    o[1] = (__bf16)(ay >= 0.f ? ay : 0.01f * ay);
    o[2] = (__bf16)(az >= 0.f ? az : 0.01f * az);
    o[3] = (__bf16)(aw >= 0.f ? aw : 0.01f * aw);
    *(bf16x4*)(hbf + (size_t)n * 256 + l * 4) = o;
}

// ---------------- GEMM2: q/k/v/s tables = hbf @ Wallt + ball ----------------
__global__ __launch_bounds__(256) void k_gemm2(const __bf16* __restrict__ hbf,
                                               const __bf16* __restrict__ Wallt,
                                               const float* __restrict__ ball,
                                               __bf16* __restrict__ qarr,
                                               __bf16* __restrict__ karr,
                                               __bf16* __restrict__ varr,
                                               __bf16* __restrict__ sarr) {
    __shared__ __bf16 As[4096];
    __shared__ __bf16 Bs[4096];
    int t = threadIdx.x;
    int lane = t & 63;
    int m = lane & 15, q = lane >> 4;
    int wave = t >> 6;
    int wr = (wave & 1) * 64;
    int wc = (wave >> 1) * 64;
    int r0 = blockIdx.x * 128;
    int c0 = blockIdx.y * 128;
    __bf16* tbl = (blockIdx.y == 0) ? qarr : (blockIdx.y == 1) ? karr
                : (blockIdx.y == 2) ? varr : sarr;

    const __bf16* asrc[2];
    __bf16* aldst[2];
#pragma unroll
    for (int j = 0; j < 2; j++) {
        int u = j * 256 + t;
        int row = r0 + (u & 127);
        if (row >= NNODES) row = NNODES - 1;
        asrc[j] = hbf + (size_t)row * HMID + (u >> 7) * 8;
        aldst[j] = &As[(size_t)u * 8];
    }
    const __bf16* bsrc[2];
    __bf16* bldst[2];
#pragma unroll
    for (int j = 0; j < 2; j++) {
        int u = j * 256 + t;
        bsrc[j] = Wallt + (size_t)(c0 + (u & 127)) * HMID + (u >> 7) * 8;
        bldst[j] = &Bs[(size_t)u * 8];
    }

    f32x4 acc[4][4] = {};

    for (int k0 = 0; k0 < HMID; k0 += 32) {
#pragma unroll
        for (int j = 0; j < 2; j++) async_copy16(asrc[j] + k0, aldst[j]);
#pragma unroll
        for (int j = 0; j < 2; j++) async_copy16(bsrc[j] + k0, bldst[j]);
        __syncthreads();

        bf16x8 af[4], bfr[4];
#pragma unroll
        for (int i = 0; i < 4; i++) af[i] = *(const bf16x8*)&As[(size_t)(q * 128 + wr + i * 16 + m) * 8];
#pragma unroll
        for (int jb = 0; jb < 4; jb++) bfr[jb] = *(const bf16x8*)&Bs[(size_t)(q * 128 + wc + jb * 16 + m) * 8];
#pragma unroll
        for (int i = 0; i < 4; i++)
#pragma unroll
            for (int jb = 0; jb < 4; jb++)
                acc[i][jb] = __builtin_amdgcn_mfma_f32_16x16x32_bf16(af[i], bfr[jb], acc[i][jb], 0, 0, 0);
        __syncthreads();
    }

#pragma unroll
    for (int jb = 0; jb < 4; jb++) {
        int dcol = wc + jb * 16 + m;
        float bias = ball[c0 + dcol];
#pragma unroll
        for (int i = 0; i < 4; i++)
#pragma unroll
            for (int r = 0; r < 4; r++) {
                int row = r0 + wr + i * 16 + q * 4 + r;
                if (row < NNODES) tbl[(size_t)row * 128 + dcol] = (__bf16)(acc[i][jb][r] + bias);
            }
    }
}

// ---------------- attention scores: per-block partial sums (NO contended atomics) ----------------
__global__ __launch_bounds__(256) void k_alpha(const int* __restrict__ rowptr,
                                               const int* __restrict__ srcsorted,
                                               const __bf16* __restrict__ qarr,
                                               const __bf16* __restrict__ karr,
                                               float* __restrict__ alpha,
                                               float* __restrict__ part) {
    int n = (blockIdx.x * 256 + threadIdx.x) >> 6;
    int lane = threadIdx.x & 63;
    int g = lane >> 4, l = lane & 15;
    float s1 = 0.f, s2 = 0.f;
    if (n < NNODES) {
        bf16x8 qb = *(const bf16x8*)(qarr + (size_t)n * 128 + l * 8);
        float qf[8];
#pragma unroll
        for (int j = 0; j < 8; j++) qf[j] = (float)qb[j];
        int beg = rowptr[n], end = rowptr[n + 1];
        for (int i = beg + g; i < end; i += 16) {
            int i1 = i + 4 < end ? i + 4 : end - 1;
            int i2 = i + 8 < end ? i + 8 : end - 1;
            int i3 = i + 12 < end ? i + 12 : end - 1;
            int s0 = srcsorted[i], sA = srcsorted[i1], sB = srcsorted[i2], sC = srcsorted[i3];
            bf16x8 k0 = *(const bf16x8*)(karr + (size_t)s0 * 128 + l * 8);
            bf16x8 k1 = *(const bf16x8*)(karr + (size_t)sA * 128 + l * 8);
            bf16x8 k2 = *(const bf16x8*)(karr + (size_t)sB * 128 + l * 8);
            bf16x8 k3 = *(const bf16x8*)(karr + (size_t)sC * 128 + l * 8);
            float d0 = 0.f, d1 = 0.f, d2 = 0.f, d3 = 0.f;
#pragma unroll
            for (int j = 0; j < 8; j++) {
                d0 += qf[j] * (float)k0[j];
                d1 += qf[j] * (float)k1[j];
                d2 += qf[j] * (float)k2[j];
                d3 += qf[j] * (float)k3[j];
            }
#pragma unroll
            for (int off = 1; off < 16; off <<= 1) {
                d0 += __shfl_xor(d0, off, 64);
                d1 += __shfl_xor(d1, off, 64);
                d2 += __shfl_xor(d2, off, 64);
                d3 += __shfl_xor(d3, off, 64);
            }
            if (l == 0) {
                const float sc = 0.08838834764831845f;  // 1/sqrt(128)
                float a0 = d0 * sc;
                alpha[i] = a0; s1 += a0; s2 += a0 * a0;
                if (i + 4 < end)  { float a = d1 * sc; alpha[i + 4]  = a; s1 += a; s2 += a * a; }
                if (i + 8 < end)  { float a = d2 * sc; alpha[i + 8]  = a; s1 += a; s2 += a * a; }
                if (i + 12 < end) { float a = d3 * sc; alpha[i + 12] = a; s1 += a; s2 += a * a; }
            }
        }
    }
#pragma unroll
    for (int off = 1; off < 64; off <<= 1) {
        s1 += __shfl_xor(s1, off, 64);
        s2 += __shfl_xor(s2, off, 64);
    }
    __shared__ float sh[8];
    int wave = threadIdx.x >> 6;
    if ((threadIdx.x & 63) == 0) { sh[wave] = s1; sh[4 + wave] = s2; }
    __syncthreads();
    if (threadIdx.x == 0) {
        part[2 * blockIdx.x]     = sh[0] + sh[1] + sh[2] + sh[3];
        part[2 * blockIdx.x + 1] = sh[4] + sh[5] + sh[6] + sh[7];
    }
}

// reduce per-block partials -> mean, 3/std  (single block, 16 waves)
__global__ __launch_bounds__(1024) void k_stats(const float* __restrict__ part,
                                                float* __restrict__ S) {
    float s1 = 0.f, s2 = 0.f;
    for (int i = threadIdx.x; i < ALPHA_BLOCKS; i += 1024) {
        s1 += part[2 * i];
        s2 += part[2 * i + 1];
    }
#pragma unroll
    for (int off = 1; off < 64; off <<= 1) {
        s1 += __shfl_xor(s1, off, 64);
        s2 += __shfl_xor(s2, off, 64);
    }
    __shared__ float sh1[16], sh2[16];
    int wave = threadIdx.x >> 6;
    if ((threadIdx.x & 63) == 0) { sh1[wave] = s1; sh2[wave] = s2; }
    __syncthreads();
    if (threadIdx.x == 0) {
        float t1 = 0.f, t2 = 0.f;
#pragma unroll
        for (int w = 0; w < 16; w++) { t1 += sh1[w]; t2 += sh2[w]; }
        float mean = t1 / (float)EEDGES;
        float var = (t2 - (float)EEDGES * mean * mean) / (float)(EEDGES - 1);
        float stdv = sqrtf(fmaxf(var, 1e-20f));
        S[2] = mean;
        S[3] = 3.0f / stdv;
    }
}

// ---------------- output gather (batch-4 MLP) ----------------
__global__ __launch_bounds__(256) void k_msg_gather(const int* __restrict__ rowptr,
                                                    const int* __restrict__ srcsorted,
                                                    const __bf16* __restrict__ varr,
                                                    const __bf16* __restrict__ sarr,
                                                    const float* __restrict__ alpha,
                                                    const float* __restrict__ S,
                                                    float* __restrict__ out) {
    int n = (blockIdx.x * 256 + threadIdx.x) >> 6;
    int l = threadIdx.x & 63;
    if (n >= NNODES) return;
    float mean = S[2], scl = S[3];
    bf16x2 sb = *(const bf16x2*)(sarr + (size_t)n * 128 + l * 2);
    float ax = (float)sb[0], ay = (float)sb[1];
    int beg = rowptr[n], end = rowptr[n + 1];
    for (int i = beg; i < end; i += 4) {
        int i1 = i + 1 < end ? i + 1 : end - 1;
        int i2 = i + 2 < end ? i + 2 : end - 1;
        int i3 = i + 3 < end ? i + 3 : end - 1;
        int s0 = srcsorted[i], s1 = srcsorted[i1], s2 = srcsorted[i2], s3 = srcsorted[i3];
        float z0 = (alpha[i] - mean) * scl;
        float z1 = (alpha[i1] - mean) * scl;
        float z2 = (alpha[i2] - mean) * scl;
        float z3 = (alpha[i3] - mean) * scl;
        float g0 = 1.0f / (1.0f + __expf(-z0));
        float g1 = (i + 1 < end) ? 1.0f / (1.0f + __expf(-z1)) : 0.f;
        float g2 = (i + 2 < end) ? 1.0f / (1.0f + __expf(-z2)) : 0.f;
        float g3 = (i + 3 < end) ? 1.0f / (1.0f + __expf(-z3)) : 0.f;
        bf16x2 v0 = *(const bf16x2*)(varr + (size_t)s0 * 128 + l * 2);
        bf16x2 v1 = *(const bf16x2*)(varr + (size_t)s1 * 128 + l * 2);
        bf16x2 v2 = *(const bf16x2*)(varr + (size_t)s2 * 128 + l * 2);
        bf16x2 v3 = *(const bf16x2*)(varr + (size_t)s3 * 128 + l * 2);
        ax += (float)v0[0] * g0 + (float)v1[0] * g1 + (float)v2[0] * g2 + (float)v3[0] * g3;
        ay += (float)v0[1] * g0 + (float)v1[1] * g1 + (float)v2[1] * g2 + (float)v3[1] * g3;
    }
    float2 o; o.x = ax; o.y = ay;
    ((float2*)(out + (size_t)n * DOUT))[l] = o;
}

// ---------------- launch ----------------
extern "C" void kernel_launch(void* const* d_in, const int* in_sizes, int n_in,
                              void* d_out, int out_size, void* d_ws, size_t ws_size,
                              hipStream_t stream) {
    const float* x  = (const float*)d_in[0];
    const int* ei   = (const int*)d_in[1];
    const int* srcI = ei;
    const int* dstI = ei + EEDGES;
    const float* Wg = (const float*)d_in[2];
    const float* bg = (const float*)d_in[3];
    const float* Wq = (const float*)d_in[4];  const float* bq = (const float*)d_in[5];
    const float* Wk = (const float*)d_in[6];  const float* bk = (const float*)d_in[7];
    const float* Wv = (const float*)d_in[8];  const float* bv = (const float*)d_in[9];
    const float* Ws = (const float*)d_in[10]; const float* bs = (const float*)d_in[11];
    float* out = (float*)d_out;

    char* wsb = (char*)d_ws;
    size_t off = 0;
    auto alloc = [&](size_t bytes) -> void* {
        void* p = wsb + off;
        off += (bytes + 255) & ~(size_t)255;
        return p;
    };
    int*    cnt    = (int*)alloc((size_t)NNODES * 4);
    int*    rowptr = (int*)alloc((size_t)(NNODES + 1) * 4);
    int*    cursor = (int*)alloc((size_t)NNODES * 4);
    int*    srcst  = (int*)alloc((size_t)EEDGES * 4);
    float*  wsort  = (float*)alloc((size_t)EEDGES * 4);
    float*  dinv   = (float*)alloc((size_t)NNODES * 4);
    float*  S      = (float*)alloc(64);
    float*  part   = (float*)alloc((size_t)ALPHA_BLOCKS * 2 * 4);
    __bf16* Wt     = (__bf16*)alloc((size_t)HMID * FIN * 2);
    __bf16* Wallt  = (__bf16*)alloc((size_t)512 * HMID * 2);
    float*  ball   = (float*)alloc(512 * 4);
    __bf16* h0bf   = (__bf16*)alloc((size_t)NNODES * HMID * 2);
    __bf16* hbf    = (__bf16*)alloc((size_t)NNODES * HMID * 2);
    __bf16* qarr   = (__bf16*)alloc((size_t)NNODES * 128 * 2);
    __bf16* karr   = (__bf16*)alloc((size_t)NNODES * 128 * 2);
    __bf16* varr   = (__bf16*)alloc((size_t)NNODES * 128 * 2);
    __bf16* sarr   = (__bf16*)alloc((size_t)NNODES * 128 * 2);
    float*  alphab = (float*)alloc((size_t)EEDGES * 4);
    if (off > ws_size) return;

    k_prep_wgcn<<<(FIN * HMID + 255) / 256, 256, 0, stream>>>(Wg, Wt);
    dim3 gw((HMID * DOUT + 255) / 256, 4);
    k_prep_watt<<<gw, 256, 0, stream>>>(Wq, Wk, Wv, Ws, bq, bk, bv, bs, Wallt, ball);

    k_init<<<(NNODES + 255) / 256, 256, 0, stream>>>(cnt, S);
    k_count<<<(EEDGES + 255) / 256, 256, 0, stream>>>(dstI, cnt);
    k_dinv<<<(NNODES + 255) / 256, 256, 0, stream>>>(cnt, dinv, cursor);
    k_scan<<<1, 1024, 0, stream>>>(cnt, rowptr);
    k_fill<<<(EEDGES + 255) / 256, 256, 0, stream>>>(srcI, dstI, rowptr, cursor, dinv, srcst, wsort);

    dim3 g1((NNODES + 127) / 128, HMID / 128);
    k_gemm1<<<g1, 256, 0, stream>>>(x, Wt, h0bf);

    k_gcn_gather<<<(NNODES * 64 + 255) / 256, 256, 0, stream>>>(rowptr, srcst, wsort, h0bf, dinv, bg, hbf);

    dim3 g2((NNODES + 127) / 128, 4);
    k_gemm2<<<g2, 256, 0, stream>>>(hbf, Wallt, ball, qarr, karr, varr, sarr);

    k_alpha<<<ALPHA_BLOCKS, 256, 0, stream>>>(rowptr, srcst, qarr, karr, alphab, part);
    k_stats<<<1, 1024, 0, stream>>>(part, S);

    k_msg_gather<<<(NNODES * 64 + 255) / 256, 256, 0, stream>>>(rowptr, srcst, varr, sarr, alphab, S, out);
}